// Round 1
// baseline (2718.867 us; speedup 1.0000x reference)
//
#include <hip/hip_runtime.h>
#include <math.h>

#define NE 8
#define IN_C 192
#define HID 384
#define OUT_C 192
#define R_C 8
#define BB 4
#define HH 128
#define WW 128
#define HW (HH * WW)        // 16384
#define NPIX (BB * HW)      // 65536
#define TILE 32

// ---------------------------------------------------------------------------
// Router: per-pixel logits (8), top-2, softmax over the two, scatter into
// per-expert (pixel, gate) lists via atomics. Lists live in d_ws.
// ---------------------------------------------------------------------------
__global__ __launch_bounds__(256) void router_kernel(
    const float* __restrict__ rin, const float* __restrict__ rW,
    const float* __restrict__ rb, int* __restrict__ counts,
    int* __restrict__ lists, float* __restrict__ gatev) {
  int pid = blockIdx.x * blockDim.x + threadIdx.x;
  if (pid >= NPIX) return;
  int b = pid >> 14;            // / HW
  int p = pid & (HW - 1);
  const float* rbase = rin + (size_t)b * R_C * HW + p;
  float r[R_C];
#pragma unroll
  for (int c = 0; c < R_C; ++c) r[c] = rbase[(size_t)c * HW];
  float lg[NE];
#pragma unroll
  for (int e = 0; e < NE; ++e) {
    float s = rb[e];
#pragma unroll
    for (int c = 0; c < R_C; ++c) s += rW[e * R_C + c] * r[c];
    lg[e] = s;
  }
  // top-1 (lowest index wins ties, matching lax.top_k)
  int e0 = 0; float l0 = lg[0];
#pragma unroll
  for (int e = 1; e < NE; ++e) { if (lg[e] > l0) { l0 = lg[e]; e0 = e; } }
  // top-2
  int e1 = -1; float l1 = -3.4e38f;
#pragma unroll
  for (int e = 0; e < NE; ++e) {
    if (e != e0 && lg[e] > l1) { l1 = lg[e]; e1 = e; }
  }
  // softmax over {l0, l1}; l0 >= l1
  float ex  = expf(l1 - l0);
  float inv = 1.0f / (1.0f + ex);
  float g0 = inv, g1 = ex * inv;

  int pos0 = atomicAdd(&counts[e0], 1);
  lists[e0 * NPIX + pos0] = pid;
  gatev[e0 * NPIX + pos0] = g0;
  int pos1 = atomicAdd(&counts[e1], 1);
  lists[e1 * NPIX + pos1] = pid;
  gatev[e1 * NPIX + pos1] = g1;
}

// ---------------------------------------------------------------------------
// Grouped MLP: block = (TILE pixels) x (one expert). fp32 vector compute.
// LDS: bufA holds x (rows [0,IN_C)) then is reused for h2; h1s separate.
// Register tile 4 outputs x 4 pixels, K stepped by 4 with float4 loads.
// ---------------------------------------------------------------------------
__global__ __launch_bounds__(512) void moe_mlp_kernel(
    const float* __restrict__ x,
    const float* __restrict__ W1, const float* __restrict__ b1,
    const float* __restrict__ W2, const float* __restrict__ b2,
    const float* __restrict__ W3, const float* __restrict__ b3,
    const int* __restrict__ counts, const int* __restrict__ lists,
    const float* __restrict__ gatev, float* __restrict__ out) {
  const int e = blockIdx.y;
  const int cnt = counts[e];
  const int start = blockIdx.x * TILE;
  if (start >= cnt) return;
  const int npt = min(TILE, cnt - start);

  __shared__ float h1s[HID][TILE];    // 48 KB
  __shared__ float bufA[HID][TILE];   // 48 KB: x tile (rows<IN_C), then h2
  __shared__ int   pb[TILE], pp[TILE];
  __shared__ float pg[TILE];

  const int tid = threadIdx.x;
  if (tid < TILE) {
    int pid = 0; float g = 0.0f;
    if (tid < npt) {
      pid = lists[e * NPIX + start + tid];
      g   = gatev[e * NPIX + start + tid];
    }
    pb[tid] = pid >> 14;
    pp[tid] = pid & (HW - 1);
    pg[tid] = g;
  }
  __syncthreads();

  // stage x -> bufA[c][i]
  for (int idx = tid; idx < IN_C * TILE; idx += 512) {
    int c = idx >> 5;
    int i = idx & 31;
    float v = 0.0f;
    if (i < npt) v = x[(size_t)pb[i] * (IN_C * HW) + (size_t)c * HW + pp[i]];
    bufA[c][i] = v;
  }
  __syncthreads();

  // ---- layer 1: h1 = gelu(W1 x + b1), K = IN_C ----
  {
    const float* We = W1 + (size_t)e * HID * IN_C;
    const float* be = b1 + (size_t)e * HID;
    for (int t = tid; t < (HID / 4) * (TILE / 4); t += 512) {
      int og = t >> 3, pq = t & 7;
      int o0 = og * 4, p0 = pq * 4;
      float acc[4][4] = {};
      const float* w0 = We + (size_t)o0 * IN_C;
      for (int c = 0; c < IN_C; c += 4) {
        float4 wq[4], xq[4];
#pragma unroll
        for (int j = 0; j < 4; ++j) wq[j] = *(const float4*)(w0 + j * IN_C + c);
#pragma unroll
        for (int cc = 0; cc < 4; ++cc) xq[cc] = *(const float4*)&bufA[c + cc][p0];
#pragma unroll
        for (int j = 0; j < 4; ++j) {
          const float* wj = (const float*)&wq[j];
#pragma unroll
          for (int cc = 0; cc < 4; ++cc) {
            const float* xc = (const float*)&xq[cc];
#pragma unroll
            for (int i = 0; i < 4; ++i) acc[j][i] += wj[cc] * xc[i];
          }
        }
      }
#pragma unroll
      for (int j = 0; j < 4; ++j) {
        float bb = be[o0 + j];
#pragma unroll
        for (int i = 0; i < 4; ++i) {
          float v = acc[j][i] + bb;
          h1s[o0 + j][p0 + i] = 0.5f * v * (1.0f + erff(v * 0.70710678118654752f));
        }
      }
    }
  }
  __syncthreads();

  // ---- layer 2: h2 = gelu(W2 h1 + b2), K = HID; write into bufA ----
  {
    const float* We = W2 + (size_t)e * HID * HID;
    const float* be = b2 + (size_t)e * HID;
    for (int t = tid; t < (HID / 4) * (TILE / 4); t += 512) {
      int og = t >> 3, pq = t & 7;
      int o0 = og * 4, p0 = pq * 4;
      float acc[4][4] = {};
      const float* w0 = We + (size_t)o0 * HID;
      for (int c = 0; c < HID; c += 4) {
        float4 wq[4], xq[4];
#pragma unroll
        for (int j = 0; j < 4; ++j) wq[j] = *(const float4*)(w0 + j * HID + c);
#pragma unroll
        for (int cc = 0; cc < 4; ++cc) xq[cc] = *(const float4*)&h1s[c + cc][p0];
#pragma unroll
        for (int j = 0; j < 4; ++j) {
          const float* wj = (const float*)&wq[j];
#pragma unroll
          for (int cc = 0; cc < 4; ++cc) {
            const float* xc = (const float*)&xq[cc];
#pragma unroll
            for (int i = 0; i < 4; ++i) acc[j][i] += wj[cc] * xc[i];
          }
        }
      }
      __syncthreads();  // all reads of bufA(x) / writes ordering barrier below
#pragma unroll
      for (int j = 0; j < 4; ++j) {
        float bb = be[o0 + j];
#pragma unroll
        for (int i = 0; i < 4; ++i) {
          float v = acc[j][i] + bb;
          bufA[o0 + j][p0 + i] = 0.5f * v * (1.0f + erff(v * 0.70710678118654752f));
        }
      }
    }
  }
  __syncthreads();

  // ---- layer 3: y = W3 h2 + b3, scaled by gate, atomicAdd into out ----
  {
    const float* We = W3 + (size_t)e * OUT_C * HID;
    const float* be = b3 + (size_t)e * OUT_C;
    for (int t = tid; t < (OUT_C / 4) * (TILE / 4); t += 512) {
      int og = t >> 3, pq = t & 7;
      int o0 = og * 4, p0 = pq * 4;
      float acc[4][4] = {};
      const float* w0 = We + (size_t)o0 * HID;
      for (int c = 0; c < HID; c += 4) {
        float4 wq[4], xq[4];
#pragma unroll
        for (int j = 0; j < 4; ++j) wq[j] = *(const float4*)(w0 + j * HID + c);
#pragma unroll
        for (int cc = 0; cc < 4; ++cc) xq[cc] = *(const float4*)&bufA[c + cc][p0];
#pragma unroll
        for (int j = 0; j < 4; ++j) {
          const float* wj = (const float*)&wq[j];
#pragma unroll
          for (int cc = 0; cc < 4; ++cc) {
            const float* xc = (const float*)&xq[cc];
#pragma unroll
            for (int i = 0; i < 4; ++i) acc[j][i] += wj[cc] * xc[i];
          }
        }
      }
#pragma unroll
      for (int i = 0; i < 4; ++i) {
        int ip = p0 + i;
        if (ip < npt) {
          float g = pg[ip];
          size_t obase = (size_t)pb[ip] * (OUT_C * HW) + pp[ip];
#pragma unroll
          for (int j = 0; j < 4; ++j) {
            float v = (acc[j][i] + be[o0 + j]) * g;
            atomicAdd(&out[obase + (size_t)(o0 + j) * HW], v);
          }
        }
      }
    }
  }
}

extern "C" void kernel_launch(void* const* d_in, const int* in_sizes, int n_in,
                              void* d_out, int out_size, void* d_ws, size_t ws_size,
                              hipStream_t stream) {
  const float* x   = (const float*)d_in[0];
  const float* rin = (const float*)d_in[1];
  const float* rW  = (const float*)d_in[2];
  const float* rb  = (const float*)d_in[3];
  const float* W1  = (const float*)d_in[4];
  const float* b1  = (const float*)d_in[5];
  const float* W2  = (const float*)d_in[6];
  const float* b2  = (const float*)d_in[7];
  const float* W3  = (const float*)d_in[8];
  const float* b3  = (const float*)d_in[9];
  float* out = (float*)d_out;

  // workspace layout: [0,32) counts, [1024, 1024+2MB) lists, then gates
  char* ws = (char*)d_ws;
  int*   counts = (int*)ws;
  int*   lists  = (int*)(ws + 1024);
  float* gatev  = (float*)(ws + 1024 + (size_t)NE * NPIX * sizeof(int));

  hipMemsetAsync(counts, 0, NE * sizeof(int), stream);
  hipMemsetAsync(d_out, 0, (size_t)out_size * sizeof(float), stream);

  router_kernel<<<NPIX / 256, 256, 0, stream>>>(rin, rW, rb, counts, lists, gatev);

  dim3 grid(NPIX / TILE, NE);
  moe_mlp_kernel<<<grid, 512, 0, stream>>>(x, W1, b1, W2, b2, W3, b3,
                                           counts, lists, gatev, out);
}

// Round 2
// 1905.792 us; speedup vs baseline: 1.4266x; 1.4266x over previous
//
#include <hip/hip_runtime.h>
#include <math.h>

#define NE 8
#define IN_C 192
#define HID 384
#define OUT_C 192
#define R_C 8
#define HW 16384
#define NPIX 65536
#define TN 64

typedef _Float16 h8_t __attribute__((ext_vector_type(8)));
typedef float f32x4 __attribute__((ext_vector_type(4)));

__device__ __forceinline__ float gelu_exact(float v) {
  return 0.5f * v * (1.0f + erff(v * 0.70710678118654752f));
}

// ---------------------------------------------------------------------------
// Router: per-pixel 8 logits, top-2, 2-way softmax, scatter to expert lists.
// ---------------------------------------------------------------------------
__global__ __launch_bounds__(256) void router_kernel(
    const float* __restrict__ rin, const float* __restrict__ rW,
    const float* __restrict__ rb, int* __restrict__ counts,
    int* __restrict__ lists, float* __restrict__ gatev) {
  int pid = blockIdx.x * blockDim.x + threadIdx.x;
  if (pid >= NPIX) return;
  int b = pid >> 14;
  int p = pid & (HW - 1);
  const float* rbase = rin + (size_t)b * R_C * HW + p;
  float r[R_C];
#pragma unroll
  for (int c = 0; c < R_C; ++c) r[c] = rbase[(size_t)c * HW];
  float lg[NE];
#pragma unroll
  for (int e = 0; e < NE; ++e) {
    float s = rb[e];
#pragma unroll
    for (int c = 0; c < R_C; ++c) s += rW[e * R_C + c] * r[c];
    lg[e] = s;
  }
  int e0 = 0; float l0 = lg[0];
#pragma unroll
  for (int e = 1; e < NE; ++e) { if (lg[e] > l0) { l0 = lg[e]; e0 = e; } }
  int e1 = -1; float l1 = -3.4e38f;
#pragma unroll
  for (int e = 0; e < NE; ++e) {
    if (e != e0 && lg[e] > l1) { l1 = lg[e]; e1 = e; }
  }
  float ex  = expf(l1 - l0);
  float inv = 1.0f / (1.0f + ex);
  float g0 = inv, g1 = ex * inv;

  int pos0 = atomicAdd(&counts[e0], 1);
  lists[e0 * NPIX + pos0] = pid;
  gatev[e0 * NPIX + pos0] = g0;
  int pos1 = atomicAdd(&counts[e1], 1);
  lists[e1 * NPIX + pos1] = pid;
  gatev[e1 * NPIX + pos1] = g1;
}

// ---------------------------------------------------------------------------
// Weight fp32 -> fp16 conversion (into d_ws).
// ---------------------------------------------------------------------------
__global__ __launch_bounds__(256) void cvt_w(const float* __restrict__ s,
                                             _Float16* __restrict__ d, int n4) {
  int i = blockIdx.x * 256 + threadIdx.x;
  if (i >= n4) return;
  float4 v = ((const float4*)s)[i];
  union { _Float16 h[4]; uint2 u; } cv;
  cv.h[0] = (_Float16)v.x; cv.h[1] = (_Float16)v.y;
  cv.h[2] = (_Float16)v.z; cv.h[3] = (_Float16)v.w;
  ((uint2*)d)[i] = cv.u;
}

// ---------------------------------------------------------------------------
// MFMA helpers. B (activations) live in LDS in slot order [K/8][TN][8]:
// element (k,n) at ((k>>3)*TN + n)*8 + (k&7). A (weights) read from global
// row-major [M][K] fp16. Both operands use the same (lane>>4, reg)->k map,
// so any hardware k-permutation cancels. M/N index = lane&15; C/D layout
// col=lane&15, row=4*(lane>>4)+reg (HW-verified).
// ---------------------------------------------------------------------------
template<int KDIM, int NM>
__device__ __forceinline__ void gemm_frag(const _Float16* __restrict__ Wg,
                                          const _Float16* __restrict__ Bsh,
                                          f32x4 (&acc)[NM][4], int m0, int lane) {
  const int l15 = lane & 15, g = lane >> 4;
#pragma unroll
  for (int kk = 0; kk < KDIM / 32; ++kk) {
    h8_t a[NM], b[4];
#pragma unroll
    for (int i = 0; i < NM; ++i)
      a[i] = *(const h8_t*)(Wg + (size_t)(m0 + i * 16 + l15) * KDIM + kk * 32 + g * 8);
#pragma unroll
    for (int nt = 0; nt < 4; ++nt)
      b[nt] = *(const h8_t*)(Bsh + ((size_t)(kk * 4 + g) * TN + nt * 16 + l15) * 8);
#pragma unroll
    for (int i = 0; i < NM; ++i)
#pragma unroll
      for (int nt = 0; nt < 4; ++nt)
        acc[i][nt] = __builtin_amdgcn_mfma_f32_16x16x32_f16(a[i], b[nt], acc[i][nt], 0, 0, 0);
  }
}

template<int NM>
__device__ __forceinline__ void act_store(f32x4 (&acc)[NM][4], const float* __restrict__ bias,
                                          _Float16* __restrict__ Dst, int m0, int lane) {
  const int l15 = lane & 15, g = lane >> 4;
#pragma unroll
  for (int i = 0; i < NM; ++i) {
    int rb = m0 + i * 16 + 4 * g;
    float4 bv = *(const float4*)(bias + rb);
#pragma unroll
    for (int nt = 0; nt < 4; ++nt) {
      int n = nt * 16 + l15;
      union { _Float16 h[4]; uint2 u; } cv;
      cv.h[0] = (_Float16)gelu_exact(acc[i][nt][0] + bv.x);
      cv.h[1] = (_Float16)gelu_exact(acc[i][nt][1] + bv.y);
      cv.h[2] = (_Float16)gelu_exact(acc[i][nt][2] + bv.z);
      cv.h[3] = (_Float16)gelu_exact(acc[i][nt][3] + bv.w);
      *(uint2*)(Dst + ((size_t)(rb >> 3) * TN + n) * 8 + (rb & 7)) = cv.u;
    }
  }
}

template<int NM>
__device__ __forceinline__ void out_store(f32x4 (&acc)[NM][4], const float* __restrict__ bias,
                                          float* __restrict__ out, const int* __restrict__ pb,
                                          const int* __restrict__ pp, const float* __restrict__ pg,
                                          int npt, int m0, int lane) {
  const int l15 = lane & 15, g = lane >> 4;
#pragma unroll
  for (int nt = 0; nt < 4; ++nt) {
    int n = nt * 16 + l15;
    if (n >= npt) continue;
    float gt = pg[n];
    size_t ob = (size_t)pb[n] * (OUT_C * HW) + pp[n];
#pragma unroll
    for (int i = 0; i < NM; ++i) {
      int rb = m0 + i * 16 + 4 * g;
      float4 bv = *(const float4*)(bias + rb);
      atomicAdd(&out[ob + (size_t)(rb + 0) * HW], (acc[i][nt][0] + bv.x) * gt);
      atomicAdd(&out[ob + (size_t)(rb + 1) * HW], (acc[i][nt][1] + bv.y) * gt);
      atomicAdd(&out[ob + (size_t)(rb + 2) * HW], (acc[i][nt][2] + bv.z) * gt);
      atomicAdd(&out[ob + (size_t)(rb + 3) * HW], (acc[i][nt][3] + bv.w) * gt);
    }
  }
}

// ---------------------------------------------------------------------------
// Fused 3-layer expert MLP on a 64-pixel tile. 8 waves, each owns an M-stripe
// across all 4 N-tiles (weights read once per block, from L2).
// LDS: H1 48KB | XS 24KB (aliased by H2 48KB after layer 1) -> 97KB.
// ---------------------------------------------------------------------------
__global__ __launch_bounds__(512, 1) void moe_mfma_kernel(
    const float* __restrict__ x,
    const _Float16* __restrict__ W1h, const float* __restrict__ b1,
    const _Float16* __restrict__ W2h, const float* __restrict__ b2,
    const _Float16* __restrict__ W3h, const float* __restrict__ b3,
    const int* __restrict__ counts, const int* __restrict__ lists,
    const float* __restrict__ gatev, float* __restrict__ out) {
  const int e = blockIdx.y;
  const int cnt = counts[e];
  const int start = blockIdx.x * TN;
  if (start >= cnt) return;
  const int npt = min(TN, cnt - start);

  __shared__ __align__(16) char smem[96 * 1024 + 1024];
  _Float16* H1 = (_Float16*)smem;                  // [48][TN][8]
  _Float16* XS = (_Float16*)(smem + 48 * 1024);    // [24][TN][8]
  _Float16* H2 = (_Float16*)(smem + 48 * 1024);    // [48][TN][8], aliases XS
  int*   pb = (int*)(smem + 96 * 1024);
  int*   pp = (int*)(smem + 96 * 1024 + 256);
  float* pg = (float*)(smem + 96 * 1024 + 512);

  const int tid = threadIdx.x;
  const int lane = tid & 63;
  const int wid = tid >> 6;

  if (tid < TN) {
    int pid = 0; float g = 0.0f;
    if (tid < npt) {
      pid = lists[e * NPIX + start + tid];
      g   = gatev[e * NPIX + start + tid];
    }
    pb[tid] = pid >> 14;
    pp[tid] = pid & (HW - 1);
    pg[tid] = g;
  }
  __syncthreads();

  // gather x (fp32, scattered columns) -> XS fragment layout, fp16
  {
    uint* XSu = (uint*)XS;
    for (int idx = tid; idx < 96 * TN; idx += 512) {
      int n = idx & (TN - 1);
      int pj = idx >> 6;          // channel pair 0..95
      int c = pj * 2;
      float v0 = 0.0f, v1 = 0.0f;
      if (n < npt) {
        const float* px = x + (size_t)pb[n] * (IN_C * HW) + (size_t)c * HW + pp[n];
        v0 = px[0];
        v1 = px[HW];
      }
      union { _Float16 h[2]; uint u; } cv;
      cv.h[0] = (_Float16)v0;
      cv.h[1] = (_Float16)v1;
      XSu[((c >> 3) * TN + n) * 4 + ((c & 7) >> 1)] = cv.u;
    }
  }
  __syncthreads();

  // layer 1: h1 = gelu(W1 x + b1), M=384 K=192
  {
    const _Float16* W1e = W1h + (size_t)e * HID * IN_C;
    f32x4 acc[3][4];
#pragma unroll
    for (int i = 0; i < 3; ++i)
#pragma unroll
      for (int nt = 0; nt < 4; ++nt) acc[i][nt] = (f32x4){0.f, 0.f, 0.f, 0.f};
    gemm_frag<IN_C, 3>(W1e, XS, acc, wid * 48, lane);
    act_store<3>(acc, b1 + e * HID, H1, wid * 48, lane);
  }
  __syncthreads();

  // layer 2: h2 = gelu(W2 h1 + b2), M=384 K=384 (writes alias XS region)
  {
    const _Float16* W2e = W2h + (size_t)e * HID * HID;
    f32x4 acc[3][4];
#pragma unroll
    for (int i = 0; i < 3; ++i)
#pragma unroll
      for (int nt = 0; nt < 4; ++nt) acc[i][nt] = (f32x4){0.f, 0.f, 0.f, 0.f};
    gemm_frag<HID, 3>(W2e, H1, acc, wid * 48, lane);
    act_store<3>(acc, b2 + e * HID, H2, wid * 48, lane);
  }
  __syncthreads();

  // layer 3: y = W3 h2 + b3, gate-scaled atomic add. M=192 K=384.
  {
    const _Float16* W3e = W3h + (size_t)e * OUT_C * HID;
    const float* b3e = b3 + e * OUT_C;
    if (wid < 4) {
      f32x4 acc[2][4];
#pragma unroll
      for (int i = 0; i < 2; ++i)
#pragma unroll
        for (int nt = 0; nt < 4; ++nt) acc[i][nt] = (f32x4){0.f, 0.f, 0.f, 0.f};
      gemm_frag<HID, 2>(W3e, H2, acc, wid * 32, lane);
      out_store<2>(acc, b3e, out, pb, pp, pg, npt, wid * 32, lane);
    } else {
      f32x4 acc[1][4];
#pragma unroll
      for (int nt = 0; nt < 4; ++nt) acc[0][nt] = (f32x4){0.f, 0.f, 0.f, 0.f};
      gemm_frag<HID, 1>(W3e, H2, acc, 128 + (wid - 4) * 16, lane);
      out_store<1>(acc, b3e, out, pb, pp, pg, npt, 128 + (wid - 4) * 16, lane);
    }
  }
}

extern "C" void kernel_launch(void* const* d_in, const int* in_sizes, int n_in,
                              void* d_out, int out_size, void* d_ws, size_t ws_size,
                              hipStream_t stream) {
  const float* x   = (const float*)d_in[0];
  const float* rin = (const float*)d_in[1];
  const float* rW  = (const float*)d_in[2];
  const float* rb  = (const float*)d_in[3];
  const float* W1  = (const float*)d_in[4];
  const float* b1  = (const float*)d_in[5];
  const float* W2  = (const float*)d_in[6];
  const float* b2  = (const float*)d_in[7];
  const float* W3  = (const float*)d_in[8];
  const float* b3  = (const float*)d_in[9];
  float* out = (float*)d_out;

  // ws layout: counts | lists (2MB) | gatev (2MB) | W1h | W2h | W3h (~9.2MB total)
  char* ws = (char*)d_ws;
  int*   counts = (int*)ws;
  int*   lists  = (int*)(ws + 1024);
  float* gatev  = (float*)(ws + 1024 + (size_t)NE * NPIX * 4);
  _Float16* W1h = (_Float16*)(ws + 1024 + 2 * (size_t)NE * NPIX * 4);
  _Float16* W2h = W1h + (size_t)NE * HID * IN_C;
  _Float16* W3h = W2h + (size_t)NE * HID * HID;

  hipMemsetAsync(counts, 0, NE * sizeof(int), stream);
  hipMemsetAsync(d_out, 0, (size_t)out_size * sizeof(float), stream);

  cvt_w<<<(NE * HID * IN_C / 4 + 255) / 256, 256, 0, stream>>>(W1, W1h, NE * HID * IN_C / 4);
  cvt_w<<<(NE * HID * HID / 4 + 255) / 256, 256, 0, stream>>>(W2, W2h, NE * HID * HID / 4);
  cvt_w<<<(NE * OUT_C * HID / 4 + 255) / 256, 256, 0, stream>>>(W3, W3h, NE * OUT_C * HID / 4);

  router_kernel<<<NPIX / 256, 256, 0, stream>>>(rin, rW, rb, counts, lists, gatev);

  dim3 grid(NPIX / TN, NE);
  moe_mfma_kernel<<<grid, 512, 0, stream>>>(x, W1h, b1, W2h, b2, W3h, b3,
                                            counts, lists, gatev, out);
}

// Round 3
// 1788.501 us; speedup vs baseline: 1.5202x; 1.0656x over previous
//
#include <hip/hip_runtime.h>
#include <math.h>

#define NE 8
#define IN_C 192
#define HID 384
#define OUT_C 192
#define R_C 8
#define HW 16384
#define NPIX 65536
#define TN 64

typedef _Float16 h8_t __attribute__((ext_vector_type(8)));
typedef float f32x4 __attribute__((ext_vector_type(4)));

__device__ __forceinline__ float gelu_exact(float v) {
  return 0.5f * v * (1.0f + erff(v * 0.70710678118654752f));
}

// ---------------------------------------------------------------------------
// Router: per-pixel 8 logits, top-2, 2-way softmax, scatter to expert lists.
// ---------------------------------------------------------------------------
__global__ __launch_bounds__(256) void router_kernel(
    const float* __restrict__ rin, const float* __restrict__ rW,
    const float* __restrict__ rb, int* __restrict__ counts,
    int* __restrict__ lists, float* __restrict__ gatev) {
  int pid = blockIdx.x * blockDim.x + threadIdx.x;
  if (pid >= NPIX) return;
  int b = pid >> 14;
  int p = pid & (HW - 1);
  const float* rbase = rin + (size_t)b * R_C * HW + p;
  float r[R_C];
#pragma unroll
  for (int c = 0; c < R_C; ++c) r[c] = rbase[(size_t)c * HW];
  float lg[NE];
#pragma unroll
  for (int e = 0; e < NE; ++e) {
    float s = rb[e];
#pragma unroll
    for (int c = 0; c < R_C; ++c) s += rW[e * R_C + c] * r[c];
    lg[e] = s;
  }
  int e0 = 0; float l0 = lg[0];
#pragma unroll
  for (int e = 1; e < NE; ++e) { if (lg[e] > l0) { l0 = lg[e]; e0 = e; } }
  int e1 = -1; float l1 = -3.4e38f;
#pragma unroll
  for (int e = 0; e < NE; ++e) {
    if (e != e0 && lg[e] > l1) { l1 = lg[e]; e1 = e; }
  }
  float ex  = expf(l1 - l0);
  float inv = 1.0f / (1.0f + ex);
  float g0 = inv, g1 = ex * inv;

  int pos0 = atomicAdd(&counts[e0], 1);
  lists[e0 * NPIX + pos0] = pid;
  gatev[e0 * NPIX + pos0] = g0;
  int pos1 = atomicAdd(&counts[e1], 1);
  lists[e1 * NPIX + pos1] = pid;
  gatev[e1 * NPIX + pos1] = g1;
}

// ---------------------------------------------------------------------------
// Weight fp32 -> fp16 conversion (into d_ws).
// ---------------------------------------------------------------------------
__global__ __launch_bounds__(256) void cvt_w(const float* __restrict__ s,
                                             _Float16* __restrict__ d, int n4) {
  int i = blockIdx.x * 256 + threadIdx.x;
  if (i >= n4) return;
  float4 v = ((const float4*)s)[i];
  union { _Float16 h[4]; uint2 u; } cv;
  cv.h[0] = (_Float16)v.x; cv.h[1] = (_Float16)v.y;
  cv.h[2] = (_Float16)v.z; cv.h[3] = (_Float16)v.w;
  ((uint2*)d)[i] = cv.u;
}

// ---------------------------------------------------------------------------
// MFMA helpers. B (activations) in LDS slot order [K/8][TN][8]: element (k,n)
// at ((k>>3)*TN + n)*8 + (k&7). A (weights) row-major [.][lda] fp16 in global
// (L2-resident via expert<->XCD affinity). Both operands use the identical
// (lane>>4, reg)->k map so any HW k-permutation cancels. C/D: col=lane&15,
// row=4*(lane>>4)+reg (HW-verified m89).
// NM frags, frag i covers rows m0 + i*MSTRIDE .. +16.
// ---------------------------------------------------------------------------
template<int KLEN, int NM, int MSTRIDE>
__device__ __forceinline__ void gemm_frag(const _Float16* __restrict__ Wg, int lda,
                                          const _Float16* __restrict__ Bsh,
                                          f32x4 (&acc)[NM][4], int m0, int lane) {
  const int l15 = lane & 15, g = lane >> 4;
#pragma unroll
  for (int kk = 0; kk < KLEN / 32; ++kk) {
    h8_t a[NM], b[4];
#pragma unroll
    for (int i = 0; i < NM; ++i)
      a[i] = *(const h8_t*)(Wg + (size_t)(m0 + i * MSTRIDE + l15) * lda + kk * 32 + g * 8);
#pragma unroll
    for (int nt = 0; nt < 4; ++nt)
      b[nt] = *(const h8_t*)(Bsh + ((size_t)(kk * 4 + g) * TN + nt * 16 + l15) * 8);
#pragma unroll
    for (int i = 0; i < NM; ++i)
#pragma unroll
      for (int nt = 0; nt < 4; ++nt)
        acc[i][nt] = __builtin_amdgcn_mfma_f32_16x16x32_f16(a[i], b[nt], acc[i][nt], 0, 0, 0);
  }
}

// gelu + fp16 pack + store to LDS fragment layout; rows are LOCAL (m0 local).
template<int NM, int MSTRIDE>
__device__ __forceinline__ void act_store(f32x4 (&acc)[NM][4], const float* __restrict__ bias,
                                          _Float16* __restrict__ Dst, int m0, int lane) {
  const int l15 = lane & 15, g = lane >> 4;
#pragma unroll
  for (int i = 0; i < NM; ++i) {
    int rb = m0 + i * MSTRIDE + 4 * g;
    float4 bv = *(const float4*)(bias + rb);
#pragma unroll
    for (int nt = 0; nt < 4; ++nt) {
      int n = nt * 16 + l15;
      union { _Float16 h[4]; uint2 u; } cv;
      cv.h[0] = (_Float16)gelu_exact(acc[i][nt][0] + bv.x);
      cv.h[1] = (_Float16)gelu_exact(acc[i][nt][1] + bv.y);
      cv.h[2] = (_Float16)gelu_exact(acc[i][nt][2] + bv.z);
      cv.h[3] = (_Float16)gelu_exact(acc[i][nt][3] + bv.w);
      *(uint2*)(Dst + ((size_t)(rb >> 3) * TN + n) * 8 + (rb & 7)) = cv.u;
    }
  }
}

template<int NM>
__device__ __forceinline__ void out_store(f32x4 (&acc)[NM][4], const float* __restrict__ bias,
                                          float* __restrict__ out, const int* __restrict__ pb,
                                          const int* __restrict__ pp, const float* __restrict__ pg,
                                          int npt, int m0, int lane) {
  const int l15 = lane & 15, g = lane >> 4;
#pragma unroll
  for (int nt = 0; nt < 4; ++nt) {
    int n = nt * 16 + l15;
    if (n >= npt) continue;
    float gt = pg[n];
    size_t ob = (size_t)pb[n] * (OUT_C * HW) + pp[n];
#pragma unroll
    for (int i = 0; i < NM; ++i) {
      int rb = m0 + i * 16 + 4 * g;
      float4 bv = *(const float4*)(bias + rb);
      atomicAdd(&out[ob + (size_t)(rb + 0) * HW], (acc[i][nt][0] + bv.x) * gt);
      atomicAdd(&out[ob + (size_t)(rb + 1) * HW], (acc[i][nt][1] + bv.y) * gt);
      atomicAdd(&out[ob + (size_t)(rb + 2) * HW], (acc[i][nt][2] + bv.z) * gt);
      atomicAdd(&out[ob + (size_t)(rb + 3) * HW], (acc[i][nt][3] + bv.w) * gt);
    }
  }
}

// ---------------------------------------------------------------------------
// Fused 3-layer expert MLP on a 64-pixel tile. 8 waves. LDS 74KB -> 2 blk/CU.
//   H1  [48][64][8] fp16 (48KB)
//   RB  [24][64][8] fp16 (24KB): X for layer1, then H2 halves (M=192 each)
// Layer 2 computed in two M=192 halves; layer 3 accumulates K in two passes.
// grid = (NE, tiles): linear bid % 8 == expert -> expert<->XCD L2 affinity.
// ---------------------------------------------------------------------------
__global__ __launch_bounds__(512, 4) void moe_mfma_kernel(
    const float* __restrict__ x,
    const _Float16* __restrict__ W1h, const float* __restrict__ b1,
    const _Float16* __restrict__ W2h, const float* __restrict__ b2,
    const _Float16* __restrict__ W3h, const float* __restrict__ b3,
    const int* __restrict__ counts, const int* __restrict__ lists,
    const float* __restrict__ gatev, float* __restrict__ out) {
  const int e = blockIdx.x;
  const int cnt = counts[e];
  const int start = blockIdx.y * TN;
  if (start >= cnt) return;
  const int npt = min(TN, cnt - start);

  __shared__ __align__(16) char smem[72 * 1024 + 768];
  _Float16* H1 = (_Float16*)smem;                  // [48][TN][8]
  _Float16* RB = (_Float16*)(smem + 48 * 1024);    // [24][TN][8]
  int*   pb = (int*)(smem + 72 * 1024);
  int*   pp = (int*)(smem + 72 * 1024 + 256);
  float* pg = (float*)(smem + 72 * 1024 + 512);

  const int tid = threadIdx.x;
  const int lane = tid & 63;
  const int wid = tid >> 6;

  if (tid < TN) {
    int pid = 0; float g = 0.0f;
    if (tid < npt) {
      pid = lists[e * NPIX + start + tid];
      g   = gatev[e * NPIX + start + tid];
    }
    pb[tid] = pid >> 14;
    pp[tid] = pid & (HW - 1);
    pg[tid] = g;
  }
  __syncthreads();

  // gather x (fp32, scattered columns) -> RB fragment layout, fp16
  {
    uint* RBu = (uint*)RB;
    for (int idx = tid; idx < 96 * TN; idx += 512) {
      int n = idx & (TN - 1);
      int pj = idx >> 6;          // channel pair 0..95
      int c = pj * 2;
      float v0 = 0.0f, v1 = 0.0f;
      if (n < npt) {
        const float* px = x + (size_t)pb[n] * (IN_C * HW) + (size_t)c * HW + pp[n];
        v0 = px[0];
        v1 = px[HW];
      }
      union { _Float16 h[2]; uint u; } cv;
      cv.h[0] = (_Float16)v0;
      cv.h[1] = (_Float16)v1;
      RBu[((c >> 3) * TN + n) * 4 + ((c & 7) >> 1)] = cv.u;
    }
  }
  __syncthreads();

  // ---- layer 1: H1 = gelu(W1 x + b1), M=384 K=192; wave stripe M=48 ----
  {
    const _Float16* W1e = W1h + (size_t)e * HID * IN_C;
    f32x4 acc[3][4];
#pragma unroll
    for (int i = 0; i < 3; ++i)
#pragma unroll
      for (int nt = 0; nt < 4; ++nt) acc[i][nt] = (f32x4){0.f, 0.f, 0.f, 0.f};
    gemm_frag<IN_C, 3, 16>(W1e, IN_C, RB, acc, wid * 48, lane);
    act_store<3, 16>(acc, b1 + e * HID, H1, wid * 48, lane);
  }
  __syncthreads();

  // ---- layers 2+3 interleaved: two M=192 halves of H2 through RB ----
  const _Float16* W2e = W2h + (size_t)e * HID * HID;
  const _Float16* W3e = W3h + (size_t)e * OUT_C * HID;
  const float* b2e = b2 + e * HID;
  const float* b3e = b3 + e * OUT_C;

  f32x4 acc3a[2][4];   // wid<4: 2 frags; wid>=4 uses acc3a[0] only
#pragma unroll
  for (int i = 0; i < 2; ++i)
#pragma unroll
    for (int nt = 0; nt < 4; ++nt) acc3a[i][nt] = (f32x4){0.f, 0.f, 0.f, 0.f};

#pragma unroll
  for (int h = 0; h < 2; ++h) {
    // layer 2 half h: rows [h*192, h*192+192) of h2 -> RB (local rows 0..191)
    // 12 frags: wave w owns frag w; waves 0-3 also own frag 8+w (MSTRIDE=128).
    {
      const _Float16* Wh = W2e + (size_t)h * 192 * HID;
      const float* bh = b2e + h * 192;
      if (wid < 4) {
        f32x4 acc[2][4];
#pragma unroll
        for (int i = 0; i < 2; ++i)
#pragma unroll
          for (int nt = 0; nt < 4; ++nt) acc[i][nt] = (f32x4){0.f, 0.f, 0.f, 0.f};
        gemm_frag<HID, 2, 128>(Wh, HID, H1, acc, wid * 16, lane);
        act_store<2, 128>(acc, bh, RB, wid * 16, lane);
      } else {
        f32x4 acc[1][4];
#pragma unroll
        for (int nt = 0; nt < 4; ++nt) acc[0][nt] = (f32x4){0.f, 0.f, 0.f, 0.f};
        gemm_frag<HID, 1, 16>(Wh, HID, H1, acc, wid * 16, lane);
        act_store<1, 16>(acc, bh, RB, wid * 16, lane);
      }
    }
    __syncthreads();

    // layer 3 partial: acc3 += W3[:, h*192 : h*192+192] @ H2_half
    if (wid < 4) {
      gemm_frag<192, 2, 16>(W3e + h * 192, HID, RB, acc3a, wid * 32, lane);
    } else {
      f32x4 (&a1)[1][4] = *(f32x4 (*)[1][4])&acc3a[0];
      gemm_frag<192, 1, 16>(W3e + h * 192, HID, RB, a1, 128 + (wid - 4) * 16, lane);
    }
    __syncthreads();
  }

  // ---- epilogue: gate-scaled atomic scatter ----
  if (wid < 4) {
    out_store<2>(acc3a, b3e, out, pb, pp, pg, npt, wid * 32, lane);
  } else {
    f32x4 (&a1)[1][4] = *(f32x4 (*)[1][4])&acc3a[0];
    out_store<1>(a1, b3e, out, pb, pp, pg, npt, 128 + (wid - 4) * 16, lane);
  }
}

extern "C" void kernel_launch(void* const* d_in, const int* in_sizes, int n_in,
                              void* d_out, int out_size, void* d_ws, size_t ws_size,
                              hipStream_t stream) {
  const float* x   = (const float*)d_in[0];
  const float* rin = (const float*)d_in[1];
  const float* rW  = (const float*)d_in[2];
  const float* rb  = (const float*)d_in[3];
  const float* W1  = (const float*)d_in[4];
  const float* b1  = (const float*)d_in[5];
  const float* W2  = (const float*)d_in[6];
  const float* b2  = (const float*)d_in[7];
  const float* W3  = (const float*)d_in[8];
  const float* b3  = (const float*)d_in[9];
  float* out = (float*)d_out;

  // ws layout: counts | lists (2MB) | gatev (2MB) | W1h | W2h | W3h (~9.2MB)
  char* ws = (char*)d_ws;
  int*   counts = (int*)ws;
  int*   lists  = (int*)(ws + 1024);
  float* gatev  = (float*)(ws + 1024 + (size_t)NE * NPIX * 4);
  _Float16* W1h = (_Float16*)(ws + 1024 + 2 * (size_t)NE * NPIX * 4);
  _Float16* W2h = W1h + (size_t)NE * HID * IN_C;
  _Float16* W3h = W2h + (size_t)NE * HID * HID;

  hipMemsetAsync(counts, 0, NE * sizeof(int), stream);
  hipMemsetAsync(d_out, 0, (size_t)out_size * sizeof(float), stream);

  cvt_w<<<(NE * HID * IN_C / 4 + 255) / 256, 256, 0, stream>>>(W1, W1h, NE * HID * IN_C / 4);
  cvt_w<<<(NE * HID * HID / 4 + 255) / 256, 256, 0, stream>>>(W2, W2h, NE * HID * HID / 4);
  cvt_w<<<(NE * OUT_C * HID / 4 + 255) / 256, 256, 0, stream>>>(W3, W3h, NE * OUT_C * HID / 4);

  router_kernel<<<NPIX / 256, 256, 0, stream>>>(rin, rW, rb, counts, lists, gatev);

  // grid: (expert, tile) -> linear bid % 8 == expert == XCD (L2 affinity)
  dim3 grid(NE, NPIX / TN);
  moe_mfma_kernel<<<grid, 512, 0, stream>>>(x, W1h, b1, W2h, b2, W3h, b3,
                                            counts, lists, gatev, out);
}

// Round 4
// 957.080 us; speedup vs baseline: 2.8408x; 1.8687x over previous
//
#include <hip/hip_runtime.h>
#include <math.h>

#define NE 8
#define IN_C 192
#define HID 384
#define OUT_C 192
#define R_C 8
#define HW 16384
#define NPIX 65536
#define TN 64
#define PPB 16384   // pixels per image

typedef _Float16 h8_t __attribute__((ext_vector_type(8)));
typedef float f32x4 __attribute__((ext_vector_type(4)));

__device__ __forceinline__ float gelu_exact(float v) {
  return 0.5f * v * (1.0f + erff(v * 0.70710678118654752f));
}

// ---------------------------------------------------------------------------
// Router: per-pixel 8 logits, top-2, 2-way softmax. Scatter into per-(expert,
// image) lists; entry = p_local | (slot << 14).
// ---------------------------------------------------------------------------
__global__ __launch_bounds__(256) void router_kernel(
    const float* __restrict__ rin, const float* __restrict__ rW,
    const float* __restrict__ rb, int* __restrict__ counts,
    int* __restrict__ lists, float* __restrict__ gatev) {
  int pid = blockIdx.x * blockDim.x + threadIdx.x;
  if (pid >= NPIX) return;
  int b = pid >> 14;
  int p = pid & (PPB - 1);
  const float* rbase = rin + (size_t)b * R_C * HW + p;
  float r[R_C];
#pragma unroll
  for (int c = 0; c < R_C; ++c) r[c] = rbase[(size_t)c * HW];
  float lg[NE];
#pragma unroll
  for (int e = 0; e < NE; ++e) {
    float s = rb[e];
#pragma unroll
    for (int c = 0; c < R_C; ++c) s += rW[e * R_C + c] * r[c];
    lg[e] = s;
  }
  int e0 = 0; float l0 = lg[0];
#pragma unroll
  for (int e = 1; e < NE; ++e) { if (lg[e] > l0) { l0 = lg[e]; e0 = e; } }
  int e1 = -1; float l1 = -3.4e38f;
#pragma unroll
  for (int e = 0; e < NE; ++e) {
    if (e != e0 && lg[e] > l1) { l1 = lg[e]; e1 = e; }
  }
  float ex  = expf(l1 - l0);
  float inv = 1.0f / (1.0f + ex);
  float g0 = inv, g1 = ex * inv;

  int pos0 = atomicAdd(&counts[e0 * 4 + b], 1);
  lists[(e0 * 4 + b) * PPB + pos0] = p;                 // slot 0
  gatev[(e0 * 4 + b) * PPB + pos0] = g0;
  int pos1 = atomicAdd(&counts[e1 * 4 + b], 1);
  lists[(e1 * 4 + b) * PPB + pos1] = p | (1 << 14);     // slot 1
  gatev[(e1 * 4 + b) * PPB + pos1] = g1;
}

// ---------------------------------------------------------------------------
// Weight fp32 -> fp16 conversion (into d_ws).
// ---------------------------------------------------------------------------
__global__ __launch_bounds__(256) void cvt_w(const float* __restrict__ s,
                                             _Float16* __restrict__ d, int n4) {
  int i = blockIdx.x * 256 + threadIdx.x;
  if (i >= n4) return;
  float4 v = ((const float4*)s)[i];
  union { _Float16 h[4]; uint2 u; } cv;
  cv.h[0] = (_Float16)v.x; cv.h[1] = (_Float16)v.y;
  cv.h[2] = (_Float16)v.z; cv.h[3] = (_Float16)v.w;
  ((uint2*)d)[i] = cv.u;
}

// ---------------------------------------------------------------------------
// MFMA helpers. B (activations) in LDS slot order [K/8][TN][8]: element (k,n)
// at ((k>>3)*TN + n)*8 + (k&7). A (weights) row-major [.][lda] fp16 in global
// (L2-resident via expert<->XCD affinity). Both operands use the identical
// (lane>>4, reg)->k map so any HW k-permutation cancels. C/D: col=lane&15,
// row=4*(lane>>4)+reg (HW-verified m89).
// ---------------------------------------------------------------------------
template<int KLEN, int NM, int MSTRIDE>
__device__ __forceinline__ void gemm_frag(const _Float16* __restrict__ Wg, int lda,
                                          const _Float16* __restrict__ Bsh,
                                          f32x4 (&acc)[NM][4], int m0, int lane) {
  const int l15 = lane & 15, g = lane >> 4;
#pragma unroll
  for (int kk = 0; kk < KLEN / 32; ++kk) {
    h8_t a[NM], b[4];
#pragma unroll
    for (int i = 0; i < NM; ++i)
      a[i] = *(const h8_t*)(Wg + (size_t)(m0 + i * MSTRIDE + l15) * lda + kk * 32 + g * 8);
#pragma unroll
    for (int nt = 0; nt < 4; ++nt)
      b[nt] = *(const h8_t*)(Bsh + ((size_t)(kk * 4 + g) * TN + nt * 16 + l15) * 8);
#pragma unroll
    for (int i = 0; i < NM; ++i)
#pragma unroll
      for (int nt = 0; nt < 4; ++nt)
        acc[i][nt] = __builtin_amdgcn_mfma_f32_16x16x32_f16(a[i], b[nt], acc[i][nt], 0, 0, 0);
  }
}

// gelu + fp16 pack + store to LDS fragment layout; rows are LOCAL (m0 local).
template<int NM, int MSTRIDE>
__device__ __forceinline__ void act_store(f32x4 (&acc)[NM][4], const float* __restrict__ bias,
                                          _Float16* __restrict__ Dst, int m0, int lane) {
  const int l15 = lane & 15, g = lane >> 4;
#pragma unroll
  for (int i = 0; i < NM; ++i) {
    int rb = m0 + i * MSTRIDE + 4 * g;
    float4 bv = *(const float4*)(bias + rb);
#pragma unroll
    for (int nt = 0; nt < 4; ++nt) {
      int n = nt * 16 + l15;
      union { _Float16 h[4]; uint2 u; } cv;
      cv.h[0] = (_Float16)gelu_exact(acc[i][nt][0] + bv.x);
      cv.h[1] = (_Float16)gelu_exact(acc[i][nt][1] + bv.y);
      cv.h[2] = (_Float16)gelu_exact(acc[i][nt][2] + bv.z);
      cv.h[3] = (_Float16)gelu_exact(acc[i][nt][3] + bv.w);
      *(uint2*)(Dst + ((size_t)(rb >> 3) * TN + n) * 8 + (rb & 7)) = cv.u;
    }
  }
}

// gated y -> fp16, dense store into ybuf[(p*2+slot)*192 + c]
template<int NM>
__device__ __forceinline__ void ybuf_store(f32x4 (&acc)[NM][4], const float* __restrict__ bias,
                                           _Float16* __restrict__ ybuf,
                                           const int* __restrict__ pidsl,
                                           const float* __restrict__ pg,
                                           int npt, int m0, int lane) {
  const int l15 = lane & 15, g = lane >> 4;
#pragma unroll
  for (int nt = 0; nt < 4; ++nt) {
    int n = nt * 16 + l15;
    if (n >= npt) continue;
    float gt = pg[n];
    _Float16* yb = ybuf + pidsl[n];
#pragma unroll
    for (int i = 0; i < NM; ++i) {
      int rb = m0 + i * 16 + 4 * g;
      float4 bv = *(const float4*)(bias + rb);
      union { _Float16 h[4]; uint2 u; } cv;
      cv.h[0] = (_Float16)((acc[i][nt][0] + bv.x) * gt);
      cv.h[1] = (_Float16)((acc[i][nt][1] + bv.y) * gt);
      cv.h[2] = (_Float16)((acc[i][nt][2] + bv.z) * gt);
      cv.h[3] = (_Float16)((acc[i][nt][3] + bv.w) * gt);
      *(uint2*)(yb + rb) = cv.u;
    }
  }
}

// ---------------------------------------------------------------------------
// Phase 1: fused 3-layer expert MLP on a 64-pixel tile of one image. 8 waves.
// LDS 74.5KB -> 2 blk/CU. grid = (NE, tiles): bid%8==expert -> XCD affinity.
// ---------------------------------------------------------------------------
__global__ __launch_bounds__(512, 4) void moe_mfma_kernel(
    const float* __restrict__ xb,          // x + b*IN_C*HW
    const _Float16* __restrict__ W1h, const float* __restrict__ b1,
    const _Float16* __restrict__ W2h, const float* __restrict__ b2,
    const _Float16* __restrict__ W3h, const float* __restrict__ b3,
    const int* __restrict__ counts, const int* __restrict__ lists,
    const float* __restrict__ gatev, _Float16* __restrict__ ybuf, int img) {
  const int e = blockIdx.x;
  const int cnt = counts[e * 4 + img];
  const int start = blockIdx.y * TN;
  if (start >= cnt) return;
  const int npt = min(TN, cnt - start);

  __shared__ __align__(16) char smem[72 * 1024 + 768];
  _Float16* H1 = (_Float16*)smem;                  // [48][TN][8]
  _Float16* RB = (_Float16*)(smem + 48 * 1024);    // [24][TN][8]
  int*   pp    = (int*)(smem + 72 * 1024);
  int*   pidsl = (int*)(smem + 72 * 1024 + 256);
  float* pg    = (float*)(smem + 72 * 1024 + 512);

  const int tid = threadIdx.x;
  const int lane = tid & 63;
  const int wid = tid >> 6;

  if (tid < TN) {
    int entry = 0; float g = 0.0f;
    if (tid < npt) {
      entry = lists[(e * 4 + img) * PPB + start + tid];
      g     = gatev[(e * 4 + img) * PPB + start + tid];
    }
    int p = entry & (PPB - 1);
    int slot = (entry >> 14) & 1;
    pp[tid] = p;
    pidsl[tid] = (p * 2 + slot) * 192;
    pg[tid] = g;
  }
  __syncthreads();

  // gather x (fp32, scattered columns) -> RB fragment layout, fp16
  {
    uint* RBu = (uint*)RB;
    for (int idx = tid; idx < 96 * TN; idx += 512) {
      int n = idx & (TN - 1);
      int c = (idx >> 6) * 2;
      float v0 = 0.0f, v1 = 0.0f;
      if (n < npt) {
        const float* px = xb + (size_t)c * HW + pp[n];
        v0 = px[0];
        v1 = px[HW];
      }
      union { _Float16 h[2]; uint u; } cv;
      cv.h[0] = (_Float16)v0;
      cv.h[1] = (_Float16)v1;
      RBu[((c >> 3) * TN + n) * 4 + ((c & 7) >> 1)] = cv.u;
    }
  }
  __syncthreads();

  // ---- layer 1: H1 = gelu(W1 x + b1), M=384 K=192; wave stripe M=48 ----
  {
    const _Float16* W1e = W1h + (size_t)e * HID * IN_C;
    f32x4 acc[3][4];
#pragma unroll
    for (int i = 0; i < 3; ++i)
#pragma unroll
      for (int nt = 0; nt < 4; ++nt) acc[i][nt] = (f32x4){0.f, 0.f, 0.f, 0.f};
    gemm_frag<IN_C, 3, 16>(W1e, IN_C, RB, acc, wid * 48, lane);
    act_store<3, 16>(acc, b1 + e * HID, H1, wid * 48, lane);
  }
  __syncthreads();

  // ---- layers 2+3 interleaved: two M=192 halves of H2 through RB ----
  const _Float16* W2e = W2h + (size_t)e * HID * HID;
  const _Float16* W3e = W3h + (size_t)e * OUT_C * HID;
  const float* b2e = b2 + e * HID;
  const float* b3e = b3 + e * OUT_C;

  f32x4 acc3a[2][4];
#pragma unroll
  for (int i = 0; i < 2; ++i)
#pragma unroll
    for (int nt = 0; nt < 4; ++nt) acc3a[i][nt] = (f32x4){0.f, 0.f, 0.f, 0.f};

#pragma unroll
  for (int h = 0; h < 2; ++h) {
    {
      const _Float16* Wh = W2e + (size_t)h * 192 * HID;
      const float* bh = b2e + h * 192;
      if (wid < 4) {
        f32x4 acc[2][4];
#pragma unroll
        for (int i = 0; i < 2; ++i)
#pragma unroll
          for (int nt = 0; nt < 4; ++nt) acc[i][nt] = (f32x4){0.f, 0.f, 0.f, 0.f};
        gemm_frag<HID, 2, 128>(Wh, HID, H1, acc, wid * 16, lane);
        act_store<2, 128>(acc, bh, RB, wid * 16, lane);
      } else {
        f32x4 acc[1][4];
#pragma unroll
        for (int nt = 0; nt < 4; ++nt) acc[0][nt] = (f32x4){0.f, 0.f, 0.f, 0.f};
        gemm_frag<HID, 1, 16>(Wh, HID, H1, acc, wid * 16, lane);
        act_store<1, 16>(acc, bh, RB, wid * 16, lane);
      }
    }
    __syncthreads();

    if (wid < 4) {
      gemm_frag<192, 2, 16>(W3e + h * 192, HID, RB, acc3a, wid * 32, lane);
    } else {
      f32x4 (&a1)[1][4] = *(f32x4 (*)[1][4])&acc3a[0];
      gemm_frag<192, 1, 16>(W3e + h * 192, HID, RB, a1, 128 + (wid - 4) * 16, lane);
    }
    __syncthreads();
  }

  // ---- epilogue: gated fp16 dense store into ybuf ----
  if (wid < 4) {
    ybuf_store<2>(acc3a, b3e, ybuf, pidsl, pg, npt, wid * 32, lane);
  } else {
    f32x4 (&a1)[1][4] = *(f32x4 (*)[1][4])&acc3a[0];
    ybuf_store<1>(a1, b3e, ybuf, pidsl, pg, npt, 128 + (wid - 4) * 16, lane);
  }
}

// ---------------------------------------------------------------------------
// Phase 2: per 64 contiguous pixels of image `img`, sum the two gated slot
// results and write out[b][c][p] coalesced (fully overwrites -> no memset).
// ---------------------------------------------------------------------------
__global__ __launch_bounds__(256) void sum_kernel(
    const _Float16* __restrict__ ybuf, float* __restrict__ out, int img) {
  __shared__ float ys[TN][193];
  const int tid = threadIdx.x;
  const int p0 = blockIdx.x * TN;

  for (int t = tid; t < TN * 48; t += 256) {
    int p = t / 48, c4 = t % 48;
    const uint2* y0 = (const uint2*)(ybuf + ((size_t)(p0 + p) * 2) * 192) + c4;
    uint2 u0 = y0[0];
    uint2 u1 = y0[48];
    union { uint2 u; _Float16 h[4]; } a, b;
    a.u = u0; b.u = u1;
#pragma unroll
    for (int j = 0; j < 4; ++j)
      ys[p][c4 * 4 + j] = (float)a.h[j] + (float)b.h[j];
  }
  __syncthreads();

  float* ob = out + (size_t)img * OUT_C * HW + p0;
  for (int t = tid; t < OUT_C * TN; t += 256) {
    int c = t >> 6, p = t & (TN - 1);
    ob[(size_t)c * HW + p] = ys[p][c];
  }
}

extern "C" void kernel_launch(void* const* d_in, const int* in_sizes, int n_in,
                              void* d_out, int out_size, void* d_ws, size_t ws_size,
                              hipStream_t stream) {
  const float* x   = (const float*)d_in[0];
  const float* rin = (const float*)d_in[1];
  const float* rW  = (const float*)d_in[2];
  const float* rb  = (const float*)d_in[3];
  const float* W1  = (const float*)d_in[4];
  const float* b1  = (const float*)d_in[5];
  const float* W2  = (const float*)d_in[6];
  const float* b2  = (const float*)d_in[7];
  const float* W3  = (const float*)d_in[8];
  const float* b3  = (const float*)d_in[9];
  float* out = (float*)d_out;

  // ws: counts(1K) | lists 2MB | gatev 2MB | W1h/W2h/W3h 9.2MB | ybuf 12.6MB
  char* ws = (char*)d_ws;
  int*   counts = (int*)ws;
  int*   lists  = (int*)(ws + 1024);
  float* gatev  = (float*)(ws + 1024 + (size_t)NE * 4 * PPB * 4);
  _Float16* W1h = (_Float16*)(ws + 1024 + 2 * (size_t)NE * 4 * PPB * 4);
  _Float16* W2h = W1h + (size_t)NE * HID * IN_C;
  _Float16* W3h = W2h + (size_t)NE * HID * HID;
  _Float16* ybuf = W3h + (size_t)NE * OUT_C * HID;   // [PPB*2][192] fp16

  hipMemsetAsync(counts, 0, NE * 4 * sizeof(int), stream);

  cvt_w<<<(NE * HID * IN_C / 4 + 255) / 256, 256, 0, stream>>>(W1, W1h, NE * HID * IN_C / 4);
  cvt_w<<<(NE * HID * HID / 4 + 255) / 256, 256, 0, stream>>>(W2, W2h, NE * HID * HID / 4);
  cvt_w<<<(NE * OUT_C * HID / 4 + 255) / 256, 256, 0, stream>>>(W3, W3h, NE * OUT_C * HID / 4);

  router_kernel<<<NPIX / 256, 256, 0, stream>>>(rin, rW, rb, counts, lists, gatev);

  for (int b = 0; b < 4; ++b) {
    dim3 grid(NE, (2 * PPB) / TN);   // generous upper bound; inactive exit
    moe_mfma_kernel<<<grid, 512, 0, stream>>>(x + (size_t)b * IN_C * HW,
                                              W1h, b1, W2h, b2, W3h, b3,
                                              counts, lists, gatev, ybuf, b);
    sum_kernel<<<PPB / TN, 256, 0, stream>>>(ybuf, out, b);
  }
}

// Round 5
// 415.255 us; speedup vs baseline: 6.5475x; 2.3048x over previous
//
#include <hip/hip_runtime.h>
#include <math.h>

#define NE 8
#define IN_C 192
#define HID 384
#define OUT_C 192
#define R_C 8
#define HW 16384
#define NPIX 65536
#define TN 64
#define PPB 16384   // pixels per image

typedef _Float16 h8_t __attribute__((ext_vector_type(8)));
typedef float f32x4 __attribute__((ext_vector_type(4)));

__device__ __forceinline__ float gelu_exact(float v) {
  return 0.5f * v * (1.0f + erff(v * 0.70710678118654752f));
}

// ---------------------------------------------------------------------------
// Router: per-pixel 8 logits, top-2, 2-way softmax. Per-block LDS histogram +
// one global atomicAdd per (block, expert) to reserve a range (contention fix:
// 131072 -> 2048 global atomics). List order is nondeterministic but every
// (pixel, slot) ybuf address is written exactly once -> output bit-exact.
// Entry = p_local | (slot << 14).
// ---------------------------------------------------------------------------
__global__ __launch_bounds__(256) void router_kernel(
    const float* __restrict__ rin, const float* __restrict__ rW,
    const float* __restrict__ rb, int* __restrict__ counts,
    int* __restrict__ lists, float* __restrict__ gatev) {
  const int tid = threadIdx.x;
  const int pid = blockIdx.x * 256 + tid;
  const int img = pid >> 14;
  const int p = pid & (PPB - 1);

  __shared__ int lcount[NE];
  __shared__ int lbase[NE];
  if (tid < NE) lcount[tid] = 0;
  __syncthreads();

  const float* rbase = rin + (size_t)img * R_C * HW + p;
  float r[R_C];
#pragma unroll
  for (int c = 0; c < R_C; ++c) r[c] = rbase[(size_t)c * HW];
  float lg[NE];
#pragma unroll
  for (int e = 0; e < NE; ++e) {
    float s = rb[e];
#pragma unroll
    for (int c = 0; c < R_C; ++c) s += rW[e * R_C + c] * r[c];
    lg[e] = s;
  }
  int e0 = 0; float l0 = lg[0];
#pragma unroll
  for (int e = 1; e < NE; ++e) { if (lg[e] > l0) { l0 = lg[e]; e0 = e; } }
  int e1 = -1; float l1 = -3.4e38f;
#pragma unroll
  for (int e = 0; e < NE; ++e) {
    if (e != e0 && lg[e] > l1) { l1 = lg[e]; e1 = e; }
  }
  float ex  = expf(l1 - l0);
  float inv = 1.0f / (1.0f + ex);
  float g0 = inv, g1 = ex * inv;

  int pos0 = atomicAdd(&lcount[e0], 1);
  int pos1 = atomicAdd(&lcount[e1], 1);
  __syncthreads();
  if (tid < NE) lbase[tid] = atomicAdd(&counts[tid * 4 + img], lcount[tid]);
  __syncthreads();

  int i0 = (e0 * 4 + img) * PPB + lbase[e0] + pos0;
  lists[i0] = p;                 // slot 0
  gatev[i0] = g0;
  int i1 = (e1 * 4 + img) * PPB + lbase[e1] + pos1;
  lists[i1] = p | (1 << 14);     // slot 1
  gatev[i1] = g1;
}

// ---------------------------------------------------------------------------
// Weight fp32 -> fp16 conversion (into d_ws).
// ---------------------------------------------------------------------------
__global__ __launch_bounds__(256) void cvt_w(const float* __restrict__ s,
                                             _Float16* __restrict__ d, int n4) {
  int i = blockIdx.x * 256 + threadIdx.x;
  if (i >= n4) return;
  float4 v = ((const float4*)s)[i];
  union { _Float16 h[4]; uint2 u; } cv;
  cv.h[0] = (_Float16)v.x; cv.h[1] = (_Float16)v.y;
  cv.h[2] = (_Float16)v.z; cv.h[3] = (_Float16)v.w;
  ((uint2*)d)[i] = cv.u;
}

// ---------------------------------------------------------------------------
// MFMA helpers. B (activations) in LDS slot order [K/8][TN][8]: element (k,n)
// at ((k>>3)*TN + n)*8 + (k&7). A (weights) row-major [.][lda] fp16 in global
// (L2-resident via expert<->XCD affinity). Both operands use the identical
// (lane>>4, reg)->k map so any HW k-permutation cancels. C/D: col=lane&15,
// row=4*(lane>>4)+reg (HW-verified m89).
// ---------------------------------------------------------------------------
template<int KLEN, int NM, int MSTRIDE>
__device__ __forceinline__ void gemm_frag(const _Float16* __restrict__ Wg, int lda,
                                          const _Float16* __restrict__ Bsh,
                                          f32x4 (&acc)[NM][4], int m0, int lane) {
  const int l15 = lane & 15, g = lane >> 4;
#pragma unroll
  for (int kk = 0; kk < KLEN / 32; ++kk) {
    h8_t a[NM], b[4];
#pragma unroll
    for (int i = 0; i < NM; ++i)
      a[i] = *(const h8_t*)(Wg + (size_t)(m0 + i * MSTRIDE + l15) * lda + kk * 32 + g * 8);
#pragma unroll
    for (int nt = 0; nt < 4; ++nt)
      b[nt] = *(const h8_t*)(Bsh + ((size_t)(kk * 4 + g) * TN + nt * 16 + l15) * 8);
#pragma unroll
    for (int i = 0; i < NM; ++i)
#pragma unroll
      for (int nt = 0; nt < 4; ++nt)
        acc[i][nt] = __builtin_amdgcn_mfma_f32_16x16x32_f16(a[i], b[nt], acc[i][nt], 0, 0, 0);
  }
}

// gelu + fp16 pack + store to LDS fragment layout; rows are LOCAL (m0 local).
template<int NM, int MSTRIDE>
__device__ __forceinline__ void act_store(f32x4 (&acc)[NM][4], const float* __restrict__ bias,
                                          _Float16* __restrict__ Dst, int m0, int lane) {
  const int l15 = lane & 15, g = lane >> 4;
#pragma unroll
  for (int i = 0; i < NM; ++i) {
    int rb = m0 + i * MSTRIDE + 4 * g;
    float4 bv = *(const float4*)(bias + rb);
#pragma unroll
    for (int nt = 0; nt < 4; ++nt) {
      int n = nt * 16 + l15;
      union { _Float16 h[4]; uint2 u; } cv;
      cv.h[0] = (_Float16)gelu_exact(acc[i][nt][0] + bv.x);
      cv.h[1] = (_Float16)gelu_exact(acc[i][nt][1] + bv.y);
      cv.h[2] = (_Float16)gelu_exact(acc[i][nt][2] + bv.z);
      cv.h[3] = (_Float16)gelu_exact(acc[i][nt][3] + bv.w);
      *(uint2*)(Dst + ((size_t)(rb >> 3) * TN + n) * 8 + (rb & 7)) = cv.u;
    }
  }
}

// gated y -> fp16, dense store into ybuf[(p*2+slot)*192 + c]
template<int NM>
__device__ __forceinline__ void ybuf_store(f32x4 (&acc)[NM][4], const float* __restrict__ bias,
                                           _Float16* __restrict__ ybuf,
                                           const int* __restrict__ pidsl,
                                           const float* __restrict__ pg,
                                           int npt, int m0, int lane) {
  const int l15 = lane & 15, g = lane >> 4;
#pragma unroll
  for (int nt = 0; nt < 4; ++nt) {
    int n = nt * 16 + l15;
    if (n >= npt) continue;
    float gt = pg[n];
    _Float16* yb = ybuf + pidsl[n];
#pragma unroll
    for (int i = 0; i < NM; ++i) {
      int rb = m0 + i * 16 + 4 * g;
      float4 bv = *(const float4*)(bias + rb);
      union { _Float16 h[4]; uint2 u; } cv;
      cv.h[0] = (_Float16)((acc[i][nt][0] + bv.x) * gt);
      cv.h[1] = (_Float16)((acc[i][nt][1] + bv.y) * gt);
      cv.h[2] = (_Float16)((acc[i][nt][2] + bv.z) * gt);
      cv.h[3] = (_Float16)((acc[i][nt][3] + bv.w) * gt);
      *(uint2*)(yb + rb) = cv.u;
    }
  }
}

// ---------------------------------------------------------------------------
// Phase 1: fused 3-layer expert MLP on a 64-pixel tile of one image. 8 waves.
// LDS 74.5KB -> 2 blk/CU. grid = (NE, tiles): bid%8==expert -> XCD affinity.
// ---------------------------------------------------------------------------
__global__ __launch_bounds__(512, 4) void moe_mfma_kernel(
    const float* __restrict__ xb,          // x + b*IN_C*HW
    const _Float16* __restrict__ W1h, const float* __restrict__ b1,
    const _Float16* __restrict__ W2h, const float* __restrict__ b2,
    const _Float16* __restrict__ W3h, const float* __restrict__ b3,
    const int* __restrict__ counts, const int* __restrict__ lists,
    const float* __restrict__ gatev, _Float16* __restrict__ ybuf, int img) {
  const int e = blockIdx.x;
  const int cnt = counts[e * 4 + img];
  const int start = blockIdx.y * TN;
  if (start >= cnt) return;
  const int npt = min(TN, cnt - start);

  __shared__ __align__(16) char smem[72 * 1024 + 768];
  _Float16* H1 = (_Float16*)smem;                  // [48][TN][8]
  _Float16* RB = (_Float16*)(smem + 48 * 1024);    // [24][TN][8]
  int*   pp    = (int*)(smem + 72 * 1024);
  int*   pidsl = (int*)(smem + 72 * 1024 + 256);
  float* pg    = (float*)(smem + 72 * 1024 + 512);

  const int tid = threadIdx.x;
  const int lane = tid & 63;
  const int wid = tid >> 6;

  if (tid < TN) {
    int entry = 0; float g = 0.0f;
    if (tid < npt) {
      entry = lists[(e * 4 + img) * PPB + start + tid];
      g     = gatev[(e * 4 + img) * PPB + start + tid];
    }
    int p = entry & (PPB - 1);
    int slot = (entry >> 14) & 1;
    pp[tid] = p;
    pidsl[tid] = (p * 2 + slot) * 192;
    pg[tid] = g;
  }
  __syncthreads();

  // gather x (fp32, scattered columns) -> RB fragment layout, fp16
  {
    uint* RBu = (uint*)RB;
    for (int idx = tid; idx < 96 * TN; idx += 512) {
      int n = idx & (TN - 1);
      int c = (idx >> 6) * 2;
      float v0 = 0.0f, v1 = 0.0f;
      if (n < npt) {
        const float* px = xb + (size_t)c * HW + pp[n];
        v0 = px[0];
        v1 = px[HW];
      }
      union { _Float16 h[2]; uint u; } cv;
      cv.h[0] = (_Float16)v0;
      cv.h[1] = (_Float16)v1;
      RBu[((c >> 3) * TN + n) * 4 + ((c & 7) >> 1)] = cv.u;
    }
  }
  __syncthreads();

  // ---- layer 1: H1 = gelu(W1 x + b1), M=384 K=192; wave stripe M=48 ----
  {
    const _Float16* W1e = W1h + (size_t)e * HID * IN_C;
    f32x4 acc[3][4];
#pragma unroll
    for (int i = 0; i < 3; ++i)
#pragma unroll
      for (int nt = 0; nt < 4; ++nt) acc[i][nt] = (f32x4){0.f, 0.f, 0.f, 0.f};
    gemm_frag<IN_C, 3, 16>(W1e, IN_C, RB, acc, wid * 48, lane);
    act_store<3, 16>(acc, b1 + e * HID, H1, wid * 48, lane);
  }
  __syncthreads();

  // ---- layers 2+3 interleaved: two M=192 halves of H2 through RB ----
  const _Float16* W2e = W2h + (size_t)e * HID * HID;
  const _Float16* W3e = W3h + (size_t)e * OUT_C * HID;
  const float* b2e = b2 + e * HID;
  const float* b3e = b3 + e * OUT_C;

  f32x4 acc3a[2][4];
#pragma unroll
  for (int i = 0; i < 2; ++i)
#pragma unroll
    for (int nt = 0; nt < 4; ++nt) acc3a[i][nt] = (f32x4){0.f, 0.f, 0.f, 0.f};

#pragma unroll
  for (int h = 0; h < 2; ++h) {
    {
      const _Float16* Wh = W2e + (size_t)h * 192 * HID;
      const float* bh = b2e + h * 192;
      if (wid < 4) {
        f32x4 acc[2][4];
#pragma unroll
        for (int i = 0; i < 2; ++i)
#pragma unroll
          for (int nt = 0; nt < 4; ++nt) acc[i][nt] = (f32x4){0.f, 0.f, 0.f, 0.f};
        gemm_frag<HID, 2, 128>(Wh, HID, H1, acc, wid * 16, lane);
        act_store<2, 128>(acc, bh, RB, wid * 16, lane);
      } else {
        f32x4 acc[1][4];
#pragma unroll
        for (int nt = 0; nt < 4; ++nt) acc[0][nt] = (f32x4){0.f, 0.f, 0.f, 0.f};
        gemm_frag<HID, 1, 16>(Wh, HID, H1, acc, wid * 16, lane);
        act_store<1, 16>(acc, bh, RB, wid * 16, lane);
      }
    }
    __syncthreads();

    if (wid < 4) {
      gemm_frag<192, 2, 16>(W3e + h * 192, HID, RB, acc3a, wid * 32, lane);
    } else {
      f32x4 (&a1)[1][4] = *(f32x4 (*)[1][4])&acc3a[0];
      gemm_frag<192, 1, 16>(W3e + h * 192, HID, RB, a1, 128 + (wid - 4) * 16, lane);
    }
    __syncthreads();
  }

  // ---- epilogue: gated fp16 dense store into ybuf ----
  if (wid < 4) {
    ybuf_store<2>(acc3a, b3e, ybuf, pidsl, pg, npt, wid * 32, lane);
  } else {
    f32x4 (&a1)[1][4] = *(f32x4 (*)[1][4])&acc3a[0];
    ybuf_store<1>(a1, b3e, ybuf, pidsl, pg, npt, 128 + (wid - 4) * 16, lane);
  }
}

// ---------------------------------------------------------------------------
// Phase 2: per 64 contiguous pixels of image `img`, sum the two gated slot
// results and write out[b][c][p] coalesced (fully overwrites -> no memset).
// ---------------------------------------------------------------------------
__global__ __launch_bounds__(256) void sum_kernel(
    const _Float16* __restrict__ ybuf, float* __restrict__ out, int img) {
  __shared__ float ys[TN][193];
  const int tid = threadIdx.x;
  const int p0 = blockIdx.x * TN;

  for (int t = tid; t < TN * 48; t += 256) {
    int p = t / 48, c4 = t % 48;
    const uint2* y0 = (const uint2*)(ybuf + ((size_t)(p0 + p) * 2) * 192) + c4;
    uint2 u0 = y0[0];
    uint2 u1 = y0[48];
    union { uint2 u; _Float16 h[4]; } a, b;
    a.u = u0; b.u = u1;
#pragma unroll
    for (int j = 0; j < 4; ++j)
      ys[p][c4 * 4 + j] = (float)a.h[j] + (float)b.h[j];
  }
  __syncthreads();

  float* ob = out + (size_t)img * OUT_C * HW + p0;
  for (int t = tid; t < OUT_C * TN; t += 256) {
    int c = t >> 6, p = t & (TN - 1);
    ob[(size_t)c * HW + p] = ys[p][c];
  }
}

extern "C" void kernel_launch(void* const* d_in, const int* in_sizes, int n_in,
                              void* d_out, int out_size, void* d_ws, size_t ws_size,
                              hipStream_t stream) {
  const float* x   = (const float*)d_in[0];
  const float* rin = (const float*)d_in[1];
  const float* rW  = (const float*)d_in[2];
  const float* rb  = (const float*)d_in[3];
  const float* W1  = (const float*)d_in[4];
  const float* b1  = (const float*)d_in[5];
  const float* W2  = (const float*)d_in[6];
  const float* b2  = (const float*)d_in[7];
  const float* W3  = (const float*)d_in[8];
  const float* b3  = (const float*)d_in[9];
  float* out = (float*)d_out;

  // ws: counts(1K) | lists 2MB | gatev 2MB | W1h/W2h/W3h 9.2MB | ybuf 12.6MB
  char* ws = (char*)d_ws;
  int*   counts = (int*)ws;
  int*   lists  = (int*)(ws + 1024);
  float* gatev  = (float*)(ws + 1024 + (size_t)NE * 4 * PPB * 4);
  _Float16* W1h = (_Float16*)(ws + 1024 + 2 * (size_t)NE * 4 * PPB * 4);
  _Float16* W2h = W1h + (size_t)NE * HID * IN_C;
  _Float16* W3h = W2h + (size_t)NE * HID * HID;
  _Float16* ybuf = W3h + (size_t)NE * OUT_C * HID;   // [PPB*2][192] fp16

  hipMemsetAsync(counts, 0, NE * 4 * sizeof(int), stream);

  cvt_w<<<(NE * HID * IN_C / 4 + 255) / 256, 256, 0, stream>>>(W1, W1h, NE * HID * IN_C / 4);
  cvt_w<<<(NE * HID * HID / 4 + 255) / 256, 256, 0, stream>>>(W2, W2h, NE * HID * HID / 4);
  cvt_w<<<(NE * OUT_C * HID / 4 + 255) / 256, 256, 0, stream>>>(W3, W3h, NE * OUT_C * HID / 4);

  router_kernel<<<NPIX / 256, 256, 0, stream>>>(rin, rW, rb, counts, lists, gatev);

  for (int b = 0; b < 4; ++b) {
    dim3 grid(NE, (2 * PPB) / TN);   // generous upper bound; inactive exit
    moe_mfma_kernel<<<grid, 512, 0, stream>>>(x + (size_t)b * IN_C * HW,
                                              W1h, b1, W2h, b2, W3h, b3,
                                              counts, lists, gatev, ybuf, b);
    sum_kernel<<<PPB / TN, 256, 0, stream>>>(ybuf, out, b);
  }
}

// Round 6
// 398.717 us; speedup vs baseline: 6.8190x; 1.0415x over previous
//
#include <hip/hip_runtime.h>
#include <math.h>

#define NE 8
#define IN_C 192
#define HID 384
#define OUT_C 192
#define R_C 8
#define HW 16384
#define NPIX 65536
#define TN 64
#define PPB 16384   // pixels per image

typedef _Float16 h8_t __attribute__((ext_vector_type(8)));
typedef float f32x4 __attribute__((ext_vector_type(4)));

__device__ __forceinline__ float gelu_exact(float v) {
  return 0.5f * v * (1.0f + erff(v * 0.70710678118654752f));
}

// ---------------------------------------------------------------------------
// Router: per-pixel 8 logits, top-2, 2-way softmax. Per-block LDS histogram +
// one global atomicAdd per (block, expert) (contention fix). Entry =
// p_local | (slot << 14). Order nondeterministic; ybuf write-once -> exact.
// ---------------------------------------------------------------------------
__global__ __launch_bounds__(256) void router_kernel(
    const float* __restrict__ rin, const float* __restrict__ rW,
    const float* __restrict__ rb, int* __restrict__ counts,
    int* __restrict__ lists, float* __restrict__ gatev) {
  const int tid = threadIdx.x;
  const int pid = blockIdx.x * 256 + tid;
  const int img = pid >> 14;
  const int p = pid & (PPB - 1);

  __shared__ int lcount[NE];
  __shared__ int lbase[NE];
  if (tid < NE) lcount[tid] = 0;
  __syncthreads();

  const float* rbase = rin + (size_t)img * R_C * HW + p;
  float r[R_C];
#pragma unroll
  for (int c = 0; c < R_C; ++c) r[c] = rbase[(size_t)c * HW];
  float lg[NE];
#pragma unroll
  for (int e = 0; e < NE; ++e) {
    float s = rb[e];
#pragma unroll
    for (int c = 0; c < R_C; ++c) s += rW[e * R_C + c] * r[c];
    lg[e] = s;
  }
  int e0 = 0; float l0 = lg[0];
#pragma unroll
  for (int e = 1; e < NE; ++e) { if (lg[e] > l0) { l0 = lg[e]; e0 = e; } }
  int e1 = -1; float l1 = -3.4e38f;
#pragma unroll
  for (int e = 0; e < NE; ++e) {
    if (e != e0 && lg[e] > l1) { l1 = lg[e]; e1 = e; }
  }
  float ex  = expf(l1 - l0);
  float inv = 1.0f / (1.0f + ex);
  float g0 = inv, g1 = ex * inv;

  int pos0 = atomicAdd(&lcount[e0], 1);
  int pos1 = atomicAdd(&lcount[e1], 1);
  __syncthreads();
  if (tid < NE) lbase[tid] = atomicAdd(&counts[tid * 4 + img], lcount[tid]);
  __syncthreads();

  int i0 = (e0 * 4 + img) * PPB + lbase[e0] + pos0;
  lists[i0] = p;                 // slot 0
  gatev[i0] = g0;
  int i1 = (e1 * 4 + img) * PPB + lbase[e1] + pos1;
  lists[i1] = p | (1 << 14);     // slot 1
  gatev[i1] = g1;
}

// ---------------------------------------------------------------------------
// Weight fp32 -> fp16 conversion (into d_ws).
// ---------------------------------------------------------------------------
__global__ __launch_bounds__(256) void cvt_w(const float* __restrict__ s,
                                             _Float16* __restrict__ d, int n4) {
  int i = blockIdx.x * 256 + threadIdx.x;
  if (i >= n4) return;
  float4 v = ((const float4*)s)[i];
  union { _Float16 h[4]; uint2 u; } cv;
  cv.h[0] = (_Float16)v.x; cv.h[1] = (_Float16)v.y;
  cv.h[2] = (_Float16)v.z; cv.h[3] = (_Float16)v.w;
  ((uint2*)d)[i] = cv.u;
}

// ---------------------------------------------------------------------------
// x transpose for one image: xb [192][16384] fp32 -> xt [16384][192] fp16.
// Reads coalesced (lanes = consecutive pixels), writes 16B/lane chunks
// (L2 write-combines the full rows across iterations).
// ---------------------------------------------------------------------------
__global__ __launch_bounds__(256) void xt_kernel(const float* __restrict__ xb,
                                                 _Float16* __restrict__ xt) {
  const int tid = threadIdx.x;
  const int p = blockIdx.x * 64 + (tid & 63);
  const int cq0 = tid >> 6;            // 0..3
#pragma unroll
  for (int cq = 0; cq < 6; ++cq) {
    int chq = cq * 4 + cq0;            // chunk 0..23 (8 channels each)
    union { _Float16 h[8]; uint4 u; } pk;
#pragma unroll
    for (int j = 0; j < 8; ++j)
      pk.h[j] = (_Float16)xb[(size_t)(chq * 8 + j) * HW + p];
    *(uint4*)(xt + (size_t)p * 192 + chq * 8) = pk.u;
  }
}

// ---------------------------------------------------------------------------
// MFMA helpers. B (activations) in LDS slot order [K/8][TN][8]: element (k,n)
// at ((k>>3)*TN + n)*8 + (k&7). A (weights) row-major [.][lda] fp16 in global
// (L2-resident via expert<->XCD affinity). Both operands use the identical
// (lane>>4, reg)->k map so any HW k-permutation cancels. C/D: col=lane&15,
// row=4*(lane>>4)+reg (HW-verified m89).
// Register double-buffered: prefetch A/B of step kk+1 while MFMA-ing kk.
// ---------------------------------------------------------------------------
template<int KLEN, int NM, int MSTRIDE>
__device__ __forceinline__ void gemm_frag(const _Float16* __restrict__ Wg, int lda,
                                          const _Float16* __restrict__ Bsh,
                                          f32x4 (&acc)[NM][4], int m0, int lane) {
  const int l15 = lane & 15, g = lane >> 4;
  constexpr int NK = KLEN / 32;
  h8_t a[2][NM], b[2][4];
#pragma unroll
  for (int i = 0; i < NM; ++i)
    a[0][i] = *(const h8_t*)(Wg + (size_t)(m0 + i * MSTRIDE + l15) * lda + g * 8);
#pragma unroll
  for (int nt = 0; nt < 4; ++nt)
    b[0][nt] = *(const h8_t*)(Bsh + ((size_t)g * TN + nt * 16 + l15) * 8);
#pragma unroll
  for (int kk = 0; kk < NK; ++kk) {
    const int cur = kk & 1, nxt = cur ^ 1;
    if (kk + 1 < NK) {
#pragma unroll
      for (int i = 0; i < NM; ++i)
        a[nxt][i] = *(const h8_t*)(Wg + (size_t)(m0 + i * MSTRIDE + l15) * lda +
                                   (kk + 1) * 32 + g * 8);
#pragma unroll
      for (int nt = 0; nt < 4; ++nt)
        b[nxt][nt] = *(const h8_t*)(Bsh + ((size_t)((kk + 1) * 4 + g) * TN + nt * 16 + l15) * 8);
    }
#pragma unroll
    for (int i = 0; i < NM; ++i)
#pragma unroll
      for (int nt = 0; nt < 4; ++nt)
        acc[i][nt] = __builtin_amdgcn_mfma_f32_16x16x32_f16(a[cur][i], b[cur][nt], acc[i][nt], 0, 0, 0);
  }
}

// gelu + fp16 pack + store to LDS fragment layout; rows are LOCAL (m0 local).
template<int NM, int MSTRIDE>
__device__ __forceinline__ void act_store(f32x4 (&acc)[NM][4], const float* __restrict__ bias,
                                          _Float16* __restrict__ Dst, int m0, int lane) {
  const int l15 = lane & 15, g = lane >> 4;
#pragma unroll
  for (int i = 0; i < NM; ++i) {
    int rb = m0 + i * MSTRIDE + 4 * g;
    float4 bv = *(const float4*)(bias + rb);
#pragma unroll
    for (int nt = 0; nt < 4; ++nt) {
      int n = nt * 16 + l15;
      union { _Float16 h[4]; uint2 u; } cv;
      cv.h[0] = (_Float16)gelu_exact(acc[i][nt][0] + bv.x);
      cv.h[1] = (_Float16)gelu_exact(acc[i][nt][1] + bv.y);
      cv.h[2] = (_Float16)gelu_exact(acc[i][nt][2] + bv.z);
      cv.h[3] = (_Float16)gelu_exact(acc[i][nt][3] + bv.w);
      *(uint2*)(Dst + ((size_t)(rb >> 3) * TN + n) * 8 + (rb & 7)) = cv.u;
    }
  }
}

// gated y -> fp16, dense store into ybuf[(p*2+slot)*192 + c]
template<int NM>
__device__ __forceinline__ void ybuf_store(f32x4 (&acc)[NM][4], const float* __restrict__ bias,
                                           _Float16* __restrict__ ybuf,
                                           const int* __restrict__ pidsl,
                                           const float* __restrict__ pg,
                                           int npt, int m0, int lane) {
  const int l15 = lane & 15, g = lane >> 4;
#pragma unroll
  for (int nt = 0; nt < 4; ++nt) {
    int n = nt * 16 + l15;
    if (n >= npt) continue;
    float gt = pg[n];
    _Float16* yb = ybuf + pidsl[n];
#pragma unroll
    for (int i = 0; i < NM; ++i) {
      int rb = m0 + i * 16 + 4 * g;
      float4 bv = *(const float4*)(bias + rb);
      union { _Float16 h[4]; uint2 u; } cv;
      cv.h[0] = (_Float16)((acc[i][nt][0] + bv.x) * gt);
      cv.h[1] = (_Float16)((acc[i][nt][1] + bv.y) * gt);
      cv.h[2] = (_Float16)((acc[i][nt][2] + bv.z) * gt);
      cv.h[3] = (_Float16)((acc[i][nt][3] + bv.w) * gt);
      *(uint2*)(yb + rb) = cv.u;
    }
  }
}

// ---------------------------------------------------------------------------
// Phase 1: fused 3-layer expert MLP on a 64-pixel tile of one image. 8 waves.
// LDS 74.5KB -> 2 blk/CU. grid = (NE, tiles): bid%8==expert -> XCD affinity.
// x comes pre-transposed fp16 [PPB][192].
// ---------------------------------------------------------------------------
__global__ __launch_bounds__(512, 4) void moe_mfma_kernel(
    const _Float16* __restrict__ xt,
    const _Float16* __restrict__ W1h, const float* __restrict__ b1,
    const _Float16* __restrict__ W2h, const float* __restrict__ b2,
    const _Float16* __restrict__ W3h, const float* __restrict__ b3,
    const int* __restrict__ counts, const int* __restrict__ lists,
    const float* __restrict__ gatev, _Float16* __restrict__ ybuf, int img) {
  const int e = blockIdx.x;
  const int cnt = counts[e * 4 + img];
  const int start = blockIdx.y * TN;
  if (start >= cnt) return;
  const int npt = min(TN, cnt - start);

  __shared__ __align__(16) char smem[72 * 1024 + 768];
  _Float16* H1 = (_Float16*)smem;                  // [48][TN][8]
  _Float16* RB = (_Float16*)(smem + 48 * 1024);    // [24][TN][8]
  int*   pp    = (int*)(smem + 72 * 1024);
  int*   pidsl = (int*)(smem + 72 * 1024 + 256);
  float* pg    = (float*)(smem + 72 * 1024 + 512);

  const int tid = threadIdx.x;
  const int lane = tid & 63;
  const int wid = tid >> 6;

  if (tid < TN) {
    int entry = 0; float g = 0.0f;
    if (tid < npt) {
      entry = lists[(e * 4 + img) * PPB + start + tid];
      g     = gatev[(e * 4 + img) * PPB + start + tid];
    }
    int p = entry & (PPB - 1);
    int slot = (entry >> 14) & 1;
    pp[tid] = p;
    pidsl[tid] = (p * 2 + slot) * 192;
    pg[tid] = g;
  }
  __syncthreads();

  // gather xt rows (fp16, 16B chunks) -> RB fragment layout
  {
    for (int i = tid; i < 24 * TN; i += 512) {   // 3 iterations
      int n = i & 63;
      int c16 = i >> 6;
      uint4 v = {0, 0, 0, 0};
      if (n < npt) v = *(const uint4*)(xt + (size_t)pp[n] * 192 + c16 * 8);
      *(uint4*)(RB + ((size_t)c16 * TN + n) * 8) = v;
    }
  }
  __syncthreads();

  // ---- layer 1: H1 = gelu(W1 x + b1), M=384 K=192; wave stripe M=48 ----
  {
    const _Float16* W1e = W1h + (size_t)e * HID * IN_C;
    f32x4 acc[3][4];
#pragma unroll
    for (int i = 0; i < 3; ++i)
#pragma unroll
      for (int nt = 0; nt < 4; ++nt) acc[i][nt] = (f32x4){0.f, 0.f, 0.f, 0.f};
    gemm_frag<IN_C, 3, 16>(W1e, IN_C, RB, acc, wid * 48, lane);
    act_store<3, 16>(acc, b1 + e * HID, H1, wid * 48, lane);
  }
  __syncthreads();

  // ---- layers 2+3 interleaved: two M=192 halves of H2 through RB ----
  const _Float16* W2e = W2h + (size_t)e * HID * HID;
  const _Float16* W3e = W3h + (size_t)e * OUT_C * HID;
  const float* b2e = b2 + e * HID;
  const float* b3e = b3 + e * OUT_C;

  f32x4 acc3a[2][4];
#pragma unroll
  for (int i = 0; i < 2; ++i)
#pragma unroll
    for (int nt = 0; nt < 4; ++nt) acc3a[i][nt] = (f32x4){0.f, 0.f, 0.f, 0.f};

#pragma unroll
  for (int h = 0; h < 2; ++h) {
    {
      const _Float16* Wh = W2e + (size_t)h * 192 * HID;
      const float* bh = b2e + h * 192;
      if (wid < 4) {
        f32x4 acc[2][4];
#pragma unroll
        for (int i = 0; i < 2; ++i)
#pragma unroll
          for (int nt = 0; nt < 4; ++nt) acc[i][nt] = (f32x4){0.f, 0.f, 0.f, 0.f};
        gemm_frag<HID, 2, 128>(Wh, HID, H1, acc, wid * 16, lane);
        act_store<2, 128>(acc, bh, RB, wid * 16, lane);
      } else {
        f32x4 acc[1][4];
#pragma unroll
        for (int nt = 0; nt < 4; ++nt) acc[0][nt] = (f32x4){0.f, 0.f, 0.f, 0.f};
        gemm_frag<HID, 1, 16>(Wh, HID, H1, acc, wid * 16, lane);
        act_store<1, 16>(acc, bh, RB, wid * 16, lane);
      }
    }
    __syncthreads();

    if (wid < 4) {
      gemm_frag<192, 2, 16>(W3e + h * 192, HID, RB, acc3a, wid * 32, lane);
    } else {
      f32x4 (&a1)[1][4] = *(f32x4 (*)[1][4])&acc3a[0];
      gemm_frag<192, 1, 16>(W3e + h * 192, HID, RB, a1, 128 + (wid - 4) * 16, lane);
    }
    __syncthreads();
  }

  // ---- epilogue: gated fp16 dense store into ybuf ----
  if (wid < 4) {
    ybuf_store<2>(acc3a, b3e, ybuf, pidsl, pg, npt, wid * 32, lane);
  } else {
    f32x4 (&a1)[1][4] = *(f32x4 (*)[1][4])&acc3a[0];
    ybuf_store<1>(a1, b3e, ybuf, pidsl, pg, npt, 128 + (wid - 4) * 16, lane);
  }
}

// ---------------------------------------------------------------------------
// Phase 2: per 64 contiguous pixels of image `img`, sum the two gated slot
// results and write out[b][c][p] coalesced (fully overwrites -> no memset).
// ---------------------------------------------------------------------------
__global__ __launch_bounds__(256) void sum_kernel(
    const _Float16* __restrict__ ybuf, float* __restrict__ out, int img) {
  __shared__ float ys[TN][193];
  const int tid = threadIdx.x;
  const int p0 = blockIdx.x * TN;

  for (int t = tid; t < TN * 48; t += 256) {
    int p = t / 48, c4 = t % 48;
    const uint2* y0 = (const uint2*)(ybuf + ((size_t)(p0 + p) * 2) * 192) + c4;
    uint2 u0 = y0[0];
    uint2 u1 = y0[48];
    union { uint2 u; _Float16 h[4]; } a, b;
    a.u = u0; b.u = u1;
#pragma unroll
    for (int j = 0; j < 4; ++j)
      ys[p][c4 * 4 + j] = (float)a.h[j] + (float)b.h[j];
  }
  __syncthreads();

  float* ob = out + (size_t)img * OUT_C * HW + p0;
  for (int t = tid; t < OUT_C * TN; t += 256) {
    int c = t >> 6, p = t & (TN - 1);
    ob[(size_t)c * HW + p] = ys[p][c];
  }
}

extern "C" void kernel_launch(void* const* d_in, const int* in_sizes, int n_in,
                              void* d_out, int out_size, void* d_ws, size_t ws_size,
                              hipStream_t stream) {
  const float* x   = (const float*)d_in[0];
  const float* rin = (const float*)d_in[1];
  const float* rW  = (const float*)d_in[2];
  const float* rb  = (const float*)d_in[3];
  const float* W1  = (const float*)d_in[4];
  const float* b1  = (const float*)d_in[5];
  const float* W2  = (const float*)d_in[6];
  const float* b2  = (const float*)d_in[7];
  const float* W3  = (const float*)d_in[8];
  const float* b3  = (const float*)d_in[9];
  float* out = (float*)d_out;

  // ws: counts 1K | lists 2MB | gatev 2MB | W 9.2MB | ybuf 12.6MB | xt 6.3MB
  char* ws = (char*)d_ws;
  int*   counts = (int*)ws;
  int*   lists  = (int*)(ws + 1024);
  float* gatev  = (float*)(ws + 1024 + (size_t)NE * 4 * PPB * 4);
  _Float16* W1h = (_Float16*)(ws + 1024 + 2 * (size_t)NE * 4 * PPB * 4);
  _Float16* W2h = W1h + (size_t)NE * HID * IN_C;
  _Float16* W3h = W2h + (size_t)NE * HID * HID;
  _Float16* ybuf = W3h + (size_t)NE * OUT_C * HID;   // [PPB*2][192] fp16
  _Float16* xt = ybuf + (size_t)PPB * 2 * 192;       // [PPB][192] fp16

  hipMemsetAsync(counts, 0, NE * 4 * sizeof(int), stream);

  cvt_w<<<(NE * HID * IN_C / 4 + 255) / 256, 256, 0, stream>>>(W1, W1h, NE * HID * IN_C / 4);
  cvt_w<<<(NE * HID * HID / 4 + 255) / 256, 256, 0, stream>>>(W2, W2h, NE * HID * HID / 4);
  cvt_w<<<(NE * OUT_C * HID / 4 + 255) / 256, 256, 0, stream>>>(W3, W3h, NE * OUT_C * HID / 4);

  router_kernel<<<NPIX / 256, 256, 0, stream>>>(rin, rW, rb, counts, lists, gatev);

  for (int b = 0; b < 4; ++b) {
    xt_kernel<<<PPB / 64, 256, 0, stream>>>(x + (size_t)b * IN_C * HW, xt);
    dim3 grid(NE, (2 * PPB) / TN);   // generous upper bound; inactive exit
    moe_mfma_kernel<<<grid, 512, 0, stream>>>(xt, W1h, b1, W2h, b2, W3h, b3,
                                              counts, lists, gatev, ybuf, b);
    sum_kernel<<<PPB / TN, 256, 0, stream>>>(ybuf, out, b);
  }
}

// Round 7
// 382.839 us; speedup vs baseline: 7.1018x; 1.0415x over previous
//
#include <hip/hip_runtime.h>
#include <math.h>

#define NE 8
#define IN_C 192
#define HID 384
#define OUT_C 192
#define R_C 8
#define HW 16384
#define NPIX 65536
#define TN 64
#define PPB 16384   // pixels per image

typedef _Float16 h8_t __attribute__((ext_vector_type(8)));
typedef float f32x4 __attribute__((ext_vector_type(4)));

// A&S 7.1.26 erf (|abs err| <= 1.5e-7) -> exact-GELU within fp32 noise.
__device__ __forceinline__ float gelu_exact(float v) {
  float z  = v * 0.70710678118654752f;
  float az = fabsf(z);
  float t  = __builtin_amdgcn_rcpf(1.0f + 0.3275911f * az);
  float p  = ((((1.061405429f * t - 1.453152027f) * t + 1.421413741f) * t
               - 0.284496736f) * t + 0.254829592f) * t;
  float er = 1.0f - p * __expf(-z * z);
  er = copysignf(er, z);
  return 0.5f * v * (1.0f + er);
}

// ---------------------------------------------------------------------------
// Router: per-pixel 8 logits, top-2, 2-way softmax. Per-block LDS histogram +
// one global atomicAdd per (block, expert). Entry = p_local | (slot << 14).
// ---------------------------------------------------------------------------
__global__ __launch_bounds__(256) void router_kernel(
    const float* __restrict__ rin, const float* __restrict__ rW,
    const float* __restrict__ rb, int* __restrict__ counts,
    int* __restrict__ lists, float* __restrict__ gatev) {
  const int tid = threadIdx.x;
  const int pid = blockIdx.x * 256 + tid;
  const int img = pid >> 14;
  const int p = pid & (PPB - 1);

  __shared__ int lcount[NE];
  __shared__ int lbase[NE];
  if (tid < NE) lcount[tid] = 0;
  __syncthreads();

  const float* rbase = rin + (size_t)img * R_C * HW + p;
  float r[R_C];
#pragma unroll
  for (int c = 0; c < R_C; ++c) r[c] = rbase[(size_t)c * HW];
  float lg[NE];
#pragma unroll
  for (int e = 0; e < NE; ++e) {
    float s = rb[e];
#pragma unroll
    for (int c = 0; c < R_C; ++c) s += rW[e * R_C + c] * r[c];
    lg[e] = s;
  }
  int e0 = 0; float l0 = lg[0];
#pragma unroll
  for (int e = 1; e < NE; ++e) { if (lg[e] > l0) { l0 = lg[e]; e0 = e; } }
  int e1 = -1; float l1 = -3.4e38f;
#pragma unroll
  for (int e = 0; e < NE; ++e) {
    if (e != e0 && lg[e] > l1) { l1 = lg[e]; e1 = e; }
  }
  float ex  = expf(l1 - l0);
  float inv = 1.0f / (1.0f + ex);
  float g0 = inv, g1 = ex * inv;

  int pos0 = atomicAdd(&lcount[e0], 1);
  int pos1 = atomicAdd(&lcount[e1], 1);
  __syncthreads();
  if (tid < NE) lbase[tid] = atomicAdd(&counts[tid * 4 + img], lcount[tid]);
  __syncthreads();

  int i0 = (e0 * 4 + img) * PPB + lbase[e0] + pos0;
  lists[i0] = p;                 // slot 0
  gatev[i0] = g0;
  int i1 = (e1 * 4 + img) * PPB + lbase[e1] + pos1;
  lists[i1] = p | (1 << 14);     // slot 1
  gatev[i1] = g1;
}

// ---------------------------------------------------------------------------
// All-weight fp32 -> fp16 conversion in one launch.
// ---------------------------------------------------------------------------
#define N1_4 (NE * HID * IN_C / 4)
#define N2_4 (NE * HID * HID / 4)
#define N3_4 (NE * OUT_C * HID / 4)
__global__ __launch_bounds__(256) void cvt_all(
    const float* __restrict__ W1, const float* __restrict__ W2,
    const float* __restrict__ W3, _Float16* __restrict__ dst) {
  int i = blockIdx.x * 256 + threadIdx.x;
  if (i >= N1_4 + N2_4 + N3_4) return;
  const float* s; _Float16* d; int j = i;
  if (j < N1_4) { s = W1; d = dst; }
  else if (j < N1_4 + N2_4) { j -= N1_4; s = W2; d = dst + (size_t)NE * HID * IN_C; }
  else { j -= N1_4 + N2_4; s = W3; d = dst + (size_t)NE * (HID * IN_C + HID * HID); }
  float4 v = ((const float4*)s)[j];
  union { _Float16 h[4]; uint2 u; } cv;
  cv.h[0] = (_Float16)v.x; cv.h[1] = (_Float16)v.y;
  cv.h[2] = (_Float16)v.z; cv.h[3] = (_Float16)v.w;
  ((uint2*)d)[j] = cv.u;
}

// ---------------------------------------------------------------------------
// x transpose for one image: xb [192][16384] fp32 -> xt [16384][192] fp16.
// ---------------------------------------------------------------------------
__global__ __launch_bounds__(256) void xt_kernel(const float* __restrict__ xb,
                                                 _Float16* __restrict__ xt) {
  const int tid = threadIdx.x;
  const int p = blockIdx.x * 64 + (tid & 63);
  const int cq0 = tid >> 6;            // 0..3
#pragma unroll
  for (int cq = 0; cq < 6; ++cq) {
    int chq = cq * 4 + cq0;            // chunk 0..23 (8 channels each)
    union { _Float16 h[8]; uint4 u; } pk;
#pragma unroll
    for (int j = 0; j < 8; ++j)
      pk.h[j] = (_Float16)xb[(size_t)(chq * 8 + j) * HW + p];
    *(uint4*)(xt + (size_t)p * 192 + chq * 8) = pk.u;
  }
}

// ---------------------------------------------------------------------------
// MFMA helpers. B (activations) in LDS slot order [K/8][TN][8]: element (k,n)
// at ((k>>3)*TN + n)*8 + (k&7). A (weights) PRELOADED into VGPRs (wload burst
// from L2-resident row-major fp16). Both operands use the identical
// (lane>>4, reg)->k map so any HW k-permutation cancels. C/D: col=lane&15,
// row=4*(lane>>4)+reg (HW-verified m89).
// ---------------------------------------------------------------------------
template<int NM, int NK, int MSTRIDE>
__device__ __forceinline__ void wload(const _Float16* __restrict__ Wg, int lda,
                                      int m0, int k0, int lane, h8_t (&w)[NM][NK]) {
  const int l15 = lane & 15, g = lane >> 4;
#pragma unroll
  for (int i = 0; i < NM; ++i)
#pragma unroll
    for (int kk = 0; kk < NK; ++kk)
      w[i][kk] = *(const h8_t*)(Wg + (size_t)(m0 + i * MSTRIDE + l15) * lda +
                                k0 + kk * 32 + g * 8);
}

template<int NM, int NK>
__device__ __forceinline__ void gemm_reg(const h8_t (&w)[NM][NK],
                                         const _Float16* __restrict__ Bsh, int kb0,
                                         f32x4 (&acc)[NM][4], int lane) {
  const int l15 = lane & 15, g = lane >> 4;
#pragma unroll
  for (int kk = 0; kk < NK; ++kk) {
    h8_t b[4];
#pragma unroll
    for (int nt = 0; nt < 4; ++nt)
      b[nt] = *(const h8_t*)(Bsh + ((size_t)((kb0 + kk) * 4 + g) * TN + nt * 16 + l15) * 8);
#pragma unroll
    for (int i = 0; i < NM; ++i)
#pragma unroll
      for (int nt = 0; nt < 4; ++nt)
        acc[i][nt] = __builtin_amdgcn_mfma_f32_16x16x32_f16(w[i][kk], b[nt], acc[i][nt], 0, 0, 0);
  }
}

// gelu + fp16 pack + store to LDS fragment layout; rows are LOCAL (m0 local).
template<int NM, int MSTRIDE>
__device__ __forceinline__ void act_store(f32x4 (&acc)[NM][4], const float* __restrict__ bias,
                                          _Float16* __restrict__ Dst, int m0, int lane) {
  const int l15 = lane & 15, g = lane >> 4;
#pragma unroll
  for (int i = 0; i < NM; ++i) {
    int rb = m0 + i * MSTRIDE + 4 * g;
    float4 bv = *(const float4*)(bias + rb);
#pragma unroll
    for (int nt = 0; nt < 4; ++nt) {
      int n = nt * 16 + l15;
      union { _Float16 h[4]; uint2 u; } cv;
      cv.h[0] = (_Float16)gelu_exact(acc[i][nt][0] + bv.x);
      cv.h[1] = (_Float16)gelu_exact(acc[i][nt][1] + bv.y);
      cv.h[2] = (_Float16)gelu_exact(acc[i][nt][2] + bv.z);
      cv.h[3] = (_Float16)gelu_exact(acc[i][nt][3] + bv.w);
      *(uint2*)(Dst + ((size_t)(rb >> 3) * TN + n) * 8 + (rb & 7)) = cv.u;
    }
  }
}

// gated y -> fp16, dense store into ybuf[(p*2+slot)*192 + c]
template<int NM>
__device__ __forceinline__ void ybuf_store(f32x4 (&acc)[NM][4], const float* __restrict__ bias,
                                           _Float16* __restrict__ ybuf,
                                           const int* __restrict__ pidsl,
                                           const float* __restrict__ pg,
                                           int npt, int m0, int lane) {
  const int l15 = lane & 15, g = lane >> 4;
#pragma unroll
  for (int nt = 0; nt < 4; ++nt) {
    int n = nt * 16 + l15;
    if (n >= npt) continue;
    float gt = pg[n];
    _Float16* yb = ybuf + pidsl[n];
#pragma unroll
    for (int i = 0; i < NM; ++i) {
      int rb = m0 + i * 16 + 4 * g;
      float4 bv = *(const float4*)(bias + rb);
      union { _Float16 h[4]; uint2 u; } cv;
      cv.h[0] = (_Float16)((acc[i][nt][0] + bv.x) * gt);
      cv.h[1] = (_Float16)((acc[i][nt][1] + bv.y) * gt);
      cv.h[2] = (_Float16)((acc[i][nt][2] + bv.z) * gt);
      cv.h[3] = (_Float16)((acc[i][nt][3] + bv.w) * gt);
      *(uint2*)(yb + rb) = cv.u;
    }
  }
}

// ---------------------------------------------------------------------------
// Phase 1: fused 3-layer expert MLP, 64-pixel tile, 8 waves, weights held in
// VGPRs per layer (K-halved preloads, peak ~160 VGPR < 256 -> 2 waves/SIMD).
// LDS: H1 48KB | RB 24KB aliased by H2 48KB -> 96.75KB, 1 blk/CU.
// Inner loops have ZERO global loads -> latency chain removed.
// grid = (NE, tiles): bid%8==expert -> XCD L2 affinity for the preloads.
// ---------------------------------------------------------------------------
__global__ __launch_bounds__(512, 2) void moe_mfma_kernel(
    const _Float16* __restrict__ xt,
    const _Float16* __restrict__ W1h, const float* __restrict__ b1,
    const _Float16* __restrict__ W2h, const float* __restrict__ b2,
    const _Float16* __restrict__ W3h, const float* __restrict__ b3,
    const int* __restrict__ counts, const int* __restrict__ lists,
    const float* __restrict__ gatev, _Float16* __restrict__ ybuf, int img) {
  const int e = blockIdx.x;
  const int cnt = counts[e * 4 + img];
  const int start = blockIdx.y * TN;
  if (start >= cnt) return;
  const int npt = min(TN, cnt - start);

  __shared__ __align__(16) char smem[96 * 1024 + 768];
  _Float16* H1 = (_Float16*)smem;                  // [48][TN][8]
  _Float16* RB = (_Float16*)(smem + 48 * 1024);    // [24][TN][8] (x tile)
  _Float16* H2 = (_Float16*)(smem + 48 * 1024);    // [48][TN][8] aliases RB+
  int*   pp    = (int*)(smem + 96 * 1024);
  int*   pidsl = (int*)(smem + 96 * 1024 + 256);
  float* pg    = (float*)(smem + 96 * 1024 + 512);

  const int tid = threadIdx.x;
  const int lane = tid & 63;
  const int wid = tid >> 6;

  if (tid < TN) {
    int entry = 0; float g = 0.0f;
    if (tid < npt) {
      entry = lists[(e * 4 + img) * PPB + start + tid];
      g     = gatev[(e * 4 + img) * PPB + start + tid];
    }
    int p = entry & (PPB - 1);
    int slot = (entry >> 14) & 1;
    pp[tid] = p;
    pidsl[tid] = (p * 2 + slot) * 192;
    pg[tid] = g;
  }
  __syncthreads();

  // gather xt rows (fp16, 16B chunks) -> RB fragment layout
  for (int i = tid; i < 24 * TN; i += 512) {   // 3 iterations
    int n = i & 63;
    int c16 = i >> 6;
    uint4 v = {0, 0, 0, 0};
    if (n < npt) v = *(const uint4*)(xt + (size_t)pp[n] * 192 + c16 * 8);
    *(uint4*)(RB + ((size_t)c16 * TN + n) * 8) = v;
  }
  __syncthreads();

  const _Float16* W1e = W1h + (size_t)e * HID * IN_C;
  const _Float16* W2e = W2h + (size_t)e * HID * HID;
  const _Float16* W3e = W3h + (size_t)e * OUT_C * HID;

  // ---- layer 1: H1 = gelu(W1 x + b1), M-stripe 48/wave, K=192 ----
  {
    h8_t w[3][6];
    wload<3, 6, 16>(W1e, IN_C, wid * 48, 0, lane, w);
    f32x4 acc[3][4];
#pragma unroll
    for (int i = 0; i < 3; ++i)
#pragma unroll
      for (int nt = 0; nt < 4; ++nt) acc[i][nt] = (f32x4){0.f, 0.f, 0.f, 0.f};
    gemm_reg<3, 6>(w, RB, 0, acc, lane);
    act_store<3, 16>(acc, b1 + e * HID, H1, wid * 48, lane);
  }
  __syncthreads();

  // ---- layer 2: H2 = gelu(W2 h1 + b2), M-stripe 48/wave, K=384 (2 halves) --
  {
    f32x4 acc[3][4];
#pragma unroll
    for (int i = 0; i < 3; ++i)
#pragma unroll
      for (int nt = 0; nt < 4; ++nt) acc[i][nt] = (f32x4){0.f, 0.f, 0.f, 0.f};
    {
      h8_t w[3][6];
      wload<3, 6, 16>(W2e, HID, wid * 48, 0, lane, w);
      gemm_reg<3, 6>(w, H1, 0, acc, lane);
      wload<3, 6, 16>(W2e, HID, wid * 48, 192, lane, w);
      gemm_reg<3, 6>(w, H1, 6, acc, lane);
    }
    // H2 writes overlap dead RB; disjoint from H1 reads of other waves.
    act_store<3, 16>(acc, b2 + e * HID, H2, wid * 48, lane);
  }
  __syncthreads();

  // ---- layer 3: y = W3 h2 + b3, K=384, gated dense store to ybuf ----
  if (wid < 4) {
    f32x4 acc[2][4];
#pragma unroll
    for (int i = 0; i < 2; ++i)
#pragma unroll
      for (int nt = 0; nt < 4; ++nt) acc[i][nt] = (f32x4){0.f, 0.f, 0.f, 0.f};
    {
      h8_t w[2][6];
      wload<2, 6, 16>(W3e, HID, wid * 32, 0, lane, w);
      gemm_reg<2, 6>(w, H2, 0, acc, lane);
      wload<2, 6, 16>(W3e, HID, wid * 32, 192, lane, w);
      gemm_reg<2, 6>(w, H2, 6, acc, lane);
    }
    ybuf_store<2>(acc, b3 + e * OUT_C, ybuf, pidsl, pg, npt, wid * 32, lane);
  } else {
    f32x4 acc[1][4];
#pragma unroll
    for (int nt = 0; nt < 4; ++nt) acc[0][nt] = (f32x4){0.f, 0.f, 0.f, 0.f};
    {
      h8_t w[1][6];
      wload<1, 6, 16>(W3e, HID, 128 + (wid - 4) * 16, 0, lane, w);
      gemm_reg<1, 6>(w, H2, 0, acc, lane);
      wload<1, 6, 16>(W3e, HID, 128 + (wid - 4) * 16, 192, lane, w);
      gemm_reg<1, 6>(w, H2, 6, acc, lane);
    }
    ybuf_store<1>(acc, b3 + e * OUT_C, ybuf, pidsl, pg, npt, 128 + (wid - 4) * 16, lane);
  }
}

// ---------------------------------------------------------------------------
// Phase 2: per 64 contiguous pixels, sum the two gated slot results and write
// out[b][c][p] coalesced (fully overwrites -> no memset needed).
// ---------------------------------------------------------------------------
__global__ __launch_bounds__(256) void sum_kernel(
    const _Float16* __restrict__ ybuf, float* __restrict__ out, int img) {
  __shared__ float ys[TN][193];
  const int tid = threadIdx.x;
  const int p0 = blockIdx.x * TN;

  for (int t = tid; t < TN * 48; t += 256) {
    int p = t / 48, c4 = t % 48;
    const uint2* y0 = (const uint2*)(ybuf + ((size_t)(p0 + p) * 2) * 192) + c4;
    uint2 u0 = y0[0];
    uint2 u1 = y0[48];
    union { uint2 u; _Float16 h[4]; } a, b;
    a.u = u0; b.u = u1;
#pragma unroll
    for (int j = 0; j < 4; ++j)
      ys[p][c4 * 4 + j] = (float)a.h[j] + (float)b.h[j];
  }
  __syncthreads();

  float* ob = out + (size_t)img * OUT_C * HW + p0;
  for (int t = tid; t < OUT_C * TN; t += 256) {
    int c = t >> 6, p = t & (TN - 1);
    ob[(size_t)c * HW + p] = ys[p][c];
  }
}

extern "C" void kernel_launch(void* const* d_in, const int* in_sizes, int n_in,
                              void* d_out, int out_size, void* d_ws, size_t ws_size,
                              hipStream_t stream) {
  const float* x   = (const float*)d_in[0];
  const float* rin = (const float*)d_in[1];
  const float* rW  = (const float*)d_in[2];
  const float* rb  = (const float*)d_in[3];
  const float* W1  = (const float*)d_in[4];
  const float* b1  = (const float*)d_in[5];
  const float* W2  = (const float*)d_in[6];
  const float* b2  = (const float*)d_in[7];
  const float* W3  = (const float*)d_in[8];
  const float* b3  = (const float*)d_in[9];
  float* out = (float*)d_out;

  // ws: counts 1K | lists 2MB | gatev 2MB | W 9.2MB | ybuf 12.6MB | xt 6.3MB
  char* ws = (char*)d_ws;
  int*   counts = (int*)ws;
  int*   lists  = (int*)(ws + 1024);
  float* gatev  = (float*)(ws + 1024 + (size_t)NE * 4 * PPB * 4);
  _Float16* W1h = (_Float16*)(ws + 1024 + 2 * (size_t)NE * 4 * PPB * 4);
  _Float16* W2h = W1h + (size_t)NE * HID * IN_C;
  _Float16* W3h = W2h + (size_t)NE * HID * HID;
  _Float16* ybuf = W3h + (size_t)NE * OUT_C * HID;   // [PPB*2][192] fp16
  _Float16* xt = ybuf + (size_t)PPB * 2 * 192;       // [PPB][192] fp16

  hipMemsetAsync(counts, 0, NE * 4 * sizeof(int), stream);

  int ncv = N1_4 + N2_4 + N3_4;
  cvt_all<<<(ncv + 255) / 256, 256, 0, stream>>>(W1, W2, W3, W1h);

  router_kernel<<<NPIX / 256, 256, 0, stream>>>(rin, rW, rb, counts, lists, gatev);

  for (int b = 0; b < 4; ++b) {
    xt_kernel<<<PPB / 64, 256, 0, stream>>>(x + (size_t)b * IN_C * HW, xt);
    dim3 grid(NE, (2 * PPB) / TN);   // generous upper bound; inactive exit
    moe_mfma_kernel<<<grid, 512, 0, stream>>>(xt, W1h, b1, W2h, b2, W3h, b3,
                                              counts, lists, gatev, ybuf, b);
    sum_kernel<<<PPB / TN, 256, 0, stream>>>(ybuf, out, b);
  }
}